// Round 2
// baseline (667.775 us; speedup 1.0000x reference)
//
#include <hip/hip_runtime.h>
#include <math.h>

// MonoFlex post-processor for MI355X — fully fused, ZERO workspace use.
// B=16, NCLS=3, CREG=50, H=96, W=320, K=100, DOWN=4, THRESH=0.2
// out = (B*K, 13) f32 rows: [cls, score, box2d(4), dims(3), loc3d(3), depth_err]
//
// One kernel, 16 blocks (one per batch), 256 threads. Per class:
//   strip-tiled NMS on logits (monotonic w/ sigmoid) -> candidate keys
//   key = (float_bits(score)<<32) | (0xFFFFFFFF - spatial_idx)
//   fused 1024-bin histogram -> suffix-scan cutoff at rank 100 -> compact
//   ~110 survivors -> bitonic-1024 sort -> per-class sorted top-100 (LDS)
// Then stage-2: re-key 300 with pos tie-break (== lax.top_k stage-2 stability),
// bitonic-512, threads 0..99 gather 50 reg channels and decode.
// Round-1 lesson: 3 MB ws writes overran ws_size and corrupted the harness's
// pristine input copy (first call right, all later calls identically wrong).
// This version touches d_ws not at all.

#define W_ 320
#define H_ 96
#define HW_ (W_ * H_)
#define NSTRIP 8
#define RPS 12            // rows per strip
#define CANDCAP 4096
#define SORTN 1024
#define BITS_02 0x3E4CCCCDu  // float bits of 0.2f

__global__ __launch_bounds__(256) void monoflex_fused(
    const float* __restrict__ hmp,
    const float* __restrict__ reg,
    const float* __restrict__ calib,
    const float* __restrict__ pad_size,
    const float* __restrict__ dim_mean,
    float* __restrict__ out) {
  const int b = blockIdx.x;   // 0..15
  const int t = threadIdx.x;  // 0..255

  __shared__ float tile[14 * 322];                     // 18032 B
  __shared__ unsigned long long candbuf[CANDCAP];      // 32768 B
  __shared__ unsigned long long sortbuf[SORTN];        // 8192 B
  __shared__ int hist[1024];                           // 4096 B
  __shared__ int part[256];                            // 1024 B
  __shared__ unsigned long long topk[300];             // 2400 B
  __shared__ unsigned long long keys[512];             // 4096 B
  __shared__ int cnt, mcnt, cutbin;

  for (int c = 0; c < 3; ++c) {
    __syncthreads();  // protect shared reuse across class iterations
    if (t == 0) { cnt = 0; mcnt = 0; cutbin = 0; }
    for (int i = t; i < 1024; i += 256) hist[i] = 0;
    __syncthreads();

    const float* plane = hmp + (size_t)(b * 3 + c) * HW_;

    for (int s = 0; s < NSTRIP; ++s) {
      const int y0 = s * RPS;
      for (int j = t; j < 14 * 322; j += 256) {
        int r = j / 322;
        int cx = j - r * 322;
        int gy = y0 - 1 + r;
        int gx = cx - 1;
        float v = -INFINITY;
        if (gy >= 0 && gy < H_ && gx >= 0 && gx < W_) v = plane[gy * W_ + gx];
        tile[j] = v;
      }
      __syncthreads();

      for (int i = t; i < RPS * W_; i += 256) {
        int r = i / W_;
        int x = i - r * W_;
        const float* t0 = &tile[r * 322 + x];
        const float* t1 = &tile[(r + 1) * 322 + x];
        const float* t2 = &tile[(r + 2) * 322 + x];
        float cv_ = t1[1];
        bool m = (cv_ >= t0[0]) && (cv_ >= t0[1]) && (cv_ >= t0[2]) &&
                 (cv_ >= t1[0]) && (cv_ >= t1[2]) &&
                 (cv_ >= t2[0]) && (cv_ >= t2[1]) && (cv_ >= t2[2]);
        if (m) {
          float sc = 1.0f / (1.0f + expf(-cv_));
          if (sc >= 0.2f) {
            unsigned gi = (unsigned)((y0 + r) * W_ + x);
            unsigned bits = __float_as_uint(sc);
            unsigned bin = (bits - BITS_02) >> 15;
            if (bin > 1023u) bin = 1023u;
            atomicAdd(&hist[bin], 1);
            int p = atomicAdd(&cnt, 1);
            if (p < CANDCAP)
              candbuf[p] = ((unsigned long long)bits << 32) |
                           (unsigned long long)(0xFFFFFFFFu - gi);
          }
        }
      }
      __syncthreads();  // before next strip overwrites tile
    }
    // cnt & hist complete here (last strip sync)

    // suffix scan over 256 chunk sums (chunk = 4 bins) to find rank-100 cutoff
    {
      int v = hist[4 * t] + hist[4 * t + 1] + hist[4 * t + 2] + hist[4 * t + 3];
      part[t] = v;
      __syncthreads();
      for (int off = 1; off < 256; off <<= 1) {
        int add = (t + off < 256) ? part[t + off] : 0;
        __syncthreads();
        part[t] += add;
        __syncthreads();
      }
      int St = part[t];
      int St1 = (t < 255) ? part[t + 1] : 0;
      if (St >= 100 && St1 < 100) {  // exactly one thread (if total >= 100)
        int acc = St1;
        for (int i = 4 * t + 3; i >= 4 * t; --i) {
          acc += hist[i];
          if (acc >= 100) { cutbin = i; break; }
        }
      }
    }
    __syncthreads();
    const int cb = cutbin;
    const int n = min(cnt, CANDCAP);

    // compact survivors (expected ~100-130)
    for (int i = t; i < n; i += 256) {
      unsigned long long k = candbuf[i];
      unsigned bits = (unsigned)(k >> 32);
      unsigned bin = (bits - BITS_02) >> 15;
      if (bin > 1023u) bin = 1023u;
      if ((int)bin >= cb) {
        int p = atomicAdd(&mcnt, 1);
        if (p < SORTN) sortbuf[p] = k;
      }
    }
    __syncthreads();
    const int m = min(mcnt, SORTN);
    for (int i = t; i < SORTN; i += 256)
      if (i >= m) sortbuf[i] = 0ULL;
    __syncthreads();

    // bitonic sort descending, N=1024 (keys unique -> deterministic)
    for (int k = 2; k <= SORTN; k <<= 1) {
      for (int j = k >> 1; j > 0; j >>= 1) {
        for (int i = t; i < SORTN; i += 256) {
          int l = i ^ j;
          if (l > i) {
            unsigned long long a = sortbuf[i], b2 = sortbuf[l];
            bool asc = (i & k) != 0;
            if ((a > b2) == asc) { sortbuf[i] = b2; sortbuf[l] = a; }
          }
        }
        __syncthreads();
      }
    }
    if (t < 100) topk[c * 100 + t] = sortbuf[t];
    // next class begins with __syncthreads()
  }
  __syncthreads();

  // ---- stage 2: top-100 of 300 with pos tie-break (class asc, rank asc) ----
  for (int i = t; i < 512; i += 256) {
    unsigned long long kk = 0ULL;
    if (i < 300) {
      unsigned bits = (unsigned)(topk[i] >> 32);
      if (bits != 0u)
        kk = ((unsigned long long)bits << 32) |
             (unsigned long long)(0xFFFFFFFFu - (unsigned)i);
    }
    keys[i] = kk;
  }
  __syncthreads();
  for (int k = 2; k <= 512; k <<= 1) {
    for (int j = k >> 1; j > 0; j >>= 1) {
      for (int i = t; i < 512; i += 256) {
        int l = i ^ j;
        if (l > i) {
          unsigned long long a = keys[i], b2 = keys[l];
          bool asc = (i & k) != 0;
          if ((a > b2) == asc) { keys[i] = b2; keys[l] = a; }
        }
      }
      __syncthreads();
    }
  }

  // ---- decode rows 0..99 ----
  if (t < 100) {
    unsigned long long key = keys[t];
    float score = __uint_as_float((unsigned)(key >> 32));
    float* orow = out + ((size_t)b * 100 + t) * 13;
    if (!(score >= 0.2f)) {
      #pragma unroll
      for (int i = 0; i < 13; ++i) orow[i] = 0.0f;
    } else {
      unsigned pos = 0xFFFFFFFFu - (unsigned)(key & 0xFFFFFFFFull);  // < 300
      int cls = (int)(pos / 100u);
      unsigned long long e = topk[pos];
      unsigned gi = 0xFFFFFFFFu - (unsigned)(e & 0xFFFFFFFFull);
      int yy = (int)(gi / W_);
      int xx = (int)gi - yy * W_;
      float x = (float)xx, y = (float)yy;

      const float* rp = reg + (size_t)b * 50 * HW_ + gi;
      float p[50];
      #pragma unroll
      for (int c = 0; c < 50; ++c) p[c] = rp[(size_t)c * HW_];

      float fu = calib[b * 4 + 0], cu = calib[b * 4 + 1];
      float fv = calib[b * 4 + 2], cv = calib[b * 4 + 3];
      float pad0 = pad_size[b * 2 + 0], pad1 = pad_size[b * 2 + 1];

      float r0 = fmaxf(p[0], 0.f), r1 = fmaxf(p[1], 0.f);
      float r2 = fmaxf(p[2], 0.f), r3 = fmaxf(p[3], 0.f);
      float bx0 = fminf(fmaxf((x - r0) * 4.f - pad0, 0.f), 1279.f);
      float by0 = fminf(fmaxf((y - r1) * 4.f - pad1, 0.f), 383.f);
      float bx1 = fminf(fmaxf((x + r2) * 4.f - pad0, 0.f), 1279.f);
      float by1 = fminf(fmaxf((y + r3) * 4.f - pad1, 0.f), 383.f);

      float d0 = expf(p[6]) * dim_mean[cls * 3 + 0];
      float d1 = expf(p[7]) * dim_mean[cls * 3 + 1];
      float d2 = expf(p[8]) * dim_mean[cls * 3 + 2];
      float h3d = d1;

      float sig = 1.0f / (1.0f + expf(-p[48]));
      float ddepth = fminf(fmaxf(1.0f / sig - 1.0f, 0.1f), 100.0f);

      float fh = fu * h3d;
      float d_ctr = fh / (fmaxf(p[42] - p[44], 0.f) * 4.f + 1e-6f);
      float d02 = 0.5f * (fh / (fmaxf(p[26] - p[34], 0.f) * 4.f + 1e-6f) +
                          fh / (fmaxf(p[30] - p[38], 0.f) * 4.f + 1e-6f));
      float d13 = 0.5f * (fh / (fmaxf(p[28] - p[36], 0.f) * 4.f + 1e-6f) +
                          fh / (fmaxf(p[32] - p[40], 0.f) * 4.f + 1e-6f));
      float kd0 = fminf(fmaxf(d_ctr, 0.1f), 100.f);
      float kd1 = fminf(fmaxf(d02, 0.1f), 100.f);
      float kd2 = fminf(fmaxf(d13, 0.1f), 100.f);

      float u0 = expf(p[49]), u1 = expf(p[45]), u2 = expf(p[46]), u3 = expf(p[47]);
      float w0 = 1.f / u0, w1 = 1.f / u1, w2 = 1.f / u2, w3 = 1.f / u3;
      float S = w0 + w1 + w2 + w3;
      float depth = (ddepth * w0 + kd0 * w1 + kd1 * w2 + kd2 * w3) / S;
      float derr = (w0 * u0 + w1 * u1 + w2 * u2 + w3 * u3) / S;

      float px = (x + p[4]) * 4.f - pad0;
      float py = (y + p[5]) * 4.f - pad1;
      float x3 = (px - cu) * depth / fu;
      float y3 = (py - cv) * depth / fv;

      orow[0] = (float)cls;
      orow[1] = score;
      orow[2] = bx0; orow[3] = by0; orow[4] = bx1; orow[5] = by1;
      orow[6] = d0;  orow[7] = d1;  orow[8] = d2;
      orow[9] = x3;  orow[10] = y3; orow[11] = depth;
      orow[12] = derr;
    }
  }
}

extern "C" void kernel_launch(void* const* d_in, const int* in_sizes, int n_in,
                              void* d_out, int out_size, void* d_ws, size_t ws_size,
                              hipStream_t stream) {
  const float* hmp   = (const float*)d_in[0];  // (16,3,96,320)
  const float* reg   = (const float*)d_in[1];  // (16,50,96,320)
  const float* calib = (const float*)d_in[2];  // (16,4)
  const float* pads  = (const float*)d_in[3];  // (16,2)
  const float* dm    = (const float*)d_in[4];  // (3,3)
  float* out = (float*)d_out;                  // 16*100*13 = 20800 floats
  (void)d_ws; (void)ws_size;                   // deliberately unused (round-1 bug)

  monoflex_fused<<<dim3(16), dim3(256), 0, stream>>>(hmp, reg, calib, pads, dm, out);
}

// Round 3
// 193.690 us; speedup vs baseline: 3.4476x; 3.4476x over previous
//
#include <hip/hip_runtime.h>
#include <math.h>

// MonoFlex post-processor for MI355X — round 3.
// B=16, NCLS=3, CREG=50, H=96, W=320, K=100, DOWN=4, THRESH=0.2
// out = (B*K, 13) f32 rows: [cls, score, box2d(4), dims(3), loc3d(3), depth_err]
//
// K1 nms_topk (48 blocks x 1024 thr): whole padded plane in LDS (126 KB),
//   NMS on logits (monotonic w/ sigmoid), candidates as u32 indices,
//   fused histogram -> suffix-scan rank-100 cutoff -> compact -> bitonic-1024
//   (1 elem/thread) -> sorted top-100 keys to ws.
//   key = (float_bits(score)<<32) | (0xFFFFFFFF - gi)  => desc sort == lax.top_k
// K2 merge_decode (16 blocks x 256): stage-2 re-key with pos tie-break
//   (== lax.top_k stage-2 stability), bitonic-512, cooperative 100x50 gather
//   into LDS, decode rows 0..99.
//
// ws use: 48*100*8 = 38,400 B only (round-1 lesson: 3 MB overran ws_size and
// corrupted the harness's pristine inputs; keep ws tiny).

#define W_ 320
#define H_ 96
#define HW_ (W_ * H_)
#define LDSW 322
#define LDSH 98
#define CANDCAP 4096
#define BITS_02 0x3E4CCCCDu  // float bits of 0.2f

__global__ __launch_bounds__(1024) void nms_topk(
    const float* __restrict__ hmp,
    unsigned long long* __restrict__ s1) {
  const int plane = blockIdx.x;  // 0..47 = b*3 + cls
  const int t = threadIdx.x;     // 0..1023
  const float* p = hmp + (size_t)plane * HW_;

  __shared__ float lp[LDSH * LDSW];             // 126,224 B padded plane
  __shared__ unsigned cand[CANDCAP];            // 16,384 B candidate indices
  __shared__ unsigned long long skey[1024];     // 8,192 B sort keys
  __shared__ int hist[1024];                    // 4,096 B
  __shared__ int part[1024];                    // 4,096 B
  __shared__ int cnt, mcnt, cutbin;

  if (t == 0) { cnt = 0; mcnt = 0; cutbin = 0; }
  hist[t] = 0;
  for (int i = t; i < LDSH * LDSW; i += 1024) lp[i] = -INFINITY;
  __syncthreads();

  // stage plane into LDS with float4 loads (rows are 80 float4s, no crossing)
  const float4* p4 = (const float4*)p;
  for (int i = t; i < HW_ / 4; i += 1024) {
    float4 v = p4[i];
    int gi0 = i * 4;
    int row = gi0 / W_;
    int col = gi0 - row * W_;
    float* d = &lp[(row + 1) * LDSW + col + 1];
    d[0] = v.x; d[1] = v.y; d[2] = v.z; d[3] = v.w;
  }
  __syncthreads();

  // NMS scan + candidate collection + score histogram
  for (int i = t; i < HW_; i += 1024) {
    int row = i / W_;
    int col = i - row * W_;
    const float* c0 = &lp[row * LDSW + col];
    const float* c1 = &lp[(row + 1) * LDSW + col];
    const float* c2 = &lp[(row + 2) * LDSW + col];
    float v = c1[1];
    bool m = (v >= c0[0]) && (v >= c0[1]) && (v >= c0[2]) &&
             (v >= c1[0]) && (v >= c1[2]) &&
             (v >= c2[0]) && (v >= c2[1]) && (v >= c2[2]);
    if (m) {
      float s = 1.0f / (1.0f + expf(-v));
      if (s >= 0.2f) {
        unsigned bits = __float_as_uint(s);
        unsigned bin = (bits - BITS_02) >> 15;
        if (bin > 1023u) bin = 1023u;
        atomicAdd(&hist[bin], 1);
        int q = atomicAdd(&cnt, 1);
        if (q < CANDCAP) cand[q] = (unsigned)i;
      }
    }
  }
  __syncthreads();

  // suffix scan over 1024 bins -> rank-100 cutoff bin
  part[t] = hist[t];
  __syncthreads();
  for (int off = 1; off < 1024; off <<= 1) {
    int add = (t + off < 1024) ? part[t + off] : 0;
    __syncthreads();
    part[t] += add;
    __syncthreads();
  }
  if (part[t] >= 100 && (t == 1023 || part[t + 1] < 100)) cutbin = t;
  __syncthreads();
  const int cb = cutbin;
  const int n = min(cnt, CANDCAP);

  // compact survivors (~110 expected), recomputing score from resident plane
  for (int i = t; i < n; i += 1024) {
    unsigned gi = cand[i];
    int row = (int)gi / W_;
    int col = (int)gi - row * W_;
    float v = lp[(row + 1) * LDSW + col + 1];
    float s = 1.0f / (1.0f + expf(-v));
    unsigned bits = __float_as_uint(s);
    unsigned bin = (bits - BITS_02) >> 15;
    if (bin > 1023u) bin = 1023u;
    if ((int)bin >= cb) {
      int q = atomicAdd(&mcnt, 1);
      if (q < 1024)
        skey[q] = ((unsigned long long)bits << 32) |
                  (unsigned long long)(0xFFFFFFFFu - gi);
    }
  }
  __syncthreads();
  const int m = min(mcnt, 1024);
  if (t >= m) skey[t] = 0ULL;
  __syncthreads();

  // bitonic sort descending, 1 element/thread (keys unique -> deterministic)
  for (int k = 2; k <= 1024; k <<= 1) {
    for (int j = k >> 1; j > 0; j >>= 1) {
      int l = t ^ j;
      if (l > t) {
        unsigned long long a = skey[t], b2 = skey[l];
        if ((a > b2) == ((t & k) != 0)) { skey[t] = b2; skey[l] = a; }
      }
      __syncthreads();
    }
  }
  if (t < 100) s1[plane * 100 + t] = skey[t];
}

__global__ __launch_bounds__(256) void merge_decode(
    const unsigned long long* __restrict__ s1,
    const float* __restrict__ reg,
    const float* __restrict__ calib,
    const float* __restrict__ pad_size,
    const float* __restrict__ dim_mean,
    float* __restrict__ out) {
  const int b = blockIdx.x;   // 0..15
  const int t = threadIdx.x;  // 0..255

  __shared__ unsigned long long topk[300];
  __shared__ unsigned long long keys[512];
  __shared__ int selgi[100];
  __shared__ int selcls[100];
  __shared__ float selsc[100];
  __shared__ float pbuf[100 * 51];  // stride 51: 51%32=19, conflict-light

  for (int i = t; i < 300; i += 256) topk[i] = s1[b * 300 + i];
  __syncthreads();
  for (int i = t; i < 512; i += 256) {
    unsigned long long kk = 0ULL;
    if (i < 300) {
      unsigned bits = (unsigned)(topk[i] >> 32);
      if (bits != 0u)
        kk = ((unsigned long long)bits << 32) |
             (unsigned long long)(0xFFFFFFFFu - (unsigned)i);
    }
    keys[i] = kk;
  }
  __syncthreads();
  // bitonic desc, N=512; tie-break = lower pos300 (class asc, rank asc)
  for (int k = 2; k <= 512; k <<= 1) {
    for (int j = k >> 1; j > 0; j >>= 1) {
      for (int i = t; i < 512; i += 256) {
        int l = i ^ j;
        if (l > i) {
          unsigned long long a = keys[i], b2 = keys[l];
          if ((a > b2) == ((i & k) != 0)) { keys[i] = b2; keys[l] = a; }
        }
      }
      __syncthreads();
    }
  }

  if (t < 100) {
    unsigned long long key = keys[t];
    float score = __uint_as_float((unsigned)(key >> 32));
    if (score >= 0.2f) {
      unsigned pos = 0xFFFFFFFFu - (unsigned)(key & 0xFFFFFFFFull);  // < 300
      selcls[t] = (int)(pos / 100u);
      unsigned long long e = topk[pos];
      selgi[t] = (int)(0xFFFFFFFFu - (unsigned)(e & 0xFFFFFFFFull));
      selsc[t] = score;
    } else {
      selgi[t] = -1;
      selcls[t] = 0;
      selsc[t] = 0.0f;
    }
  }
  __syncthreads();

  // cooperative gather: 100 rows x 50 channels, channel-major for parallel loads
  const float* rbase = reg + (size_t)b * 50 * HW_;
  for (int i = t; i < 100 * 50; i += 256) {
    int row = i % 100;
    int ch = i / 100;
    int gi = selgi[row];
    float v = 0.0f;
    if (gi >= 0) v = rbase[(size_t)ch * HW_ + gi];
    pbuf[row * 51 + ch] = v;
  }
  __syncthreads();

  if (t < 100) {
    float* orow = out + ((size_t)b * 100 + t) * 13;
    int gi = selgi[t];
    if (gi < 0) {
      #pragma unroll
      for (int i = 0; i < 13; ++i) orow[i] = 0.0f;
    } else {
      const float* p = &pbuf[t * 51];
      int cls = selcls[t];
      float score = selsc[t];
      int yy = gi / W_;
      int xx = gi - yy * W_;
      float x = (float)xx, y = (float)yy;

      float fu = calib[b * 4 + 0], cu = calib[b * 4 + 1];
      float fv = calib[b * 4 + 2], cv = calib[b * 4 + 3];
      float pad0 = pad_size[b * 2 + 0], pad1 = pad_size[b * 2 + 1];

      float r0 = fmaxf(p[0], 0.f), r1 = fmaxf(p[1], 0.f);
      float r2 = fmaxf(p[2], 0.f), r3 = fmaxf(p[3], 0.f);
      float bx0 = fminf(fmaxf((x - r0) * 4.f - pad0, 0.f), 1279.f);
      float by0 = fminf(fmaxf((y - r1) * 4.f - pad1, 0.f), 383.f);
      float bx1 = fminf(fmaxf((x + r2) * 4.f - pad0, 0.f), 1279.f);
      float by1 = fminf(fmaxf((y + r3) * 4.f - pad1, 0.f), 383.f);

      float d0 = expf(p[6]) * dim_mean[cls * 3 + 0];
      float d1 = expf(p[7]) * dim_mean[cls * 3 + 1];
      float d2 = expf(p[8]) * dim_mean[cls * 3 + 2];
      float h3d = d1;

      float sig = 1.0f / (1.0f + expf(-p[48]));
      float ddepth = fminf(fmaxf(1.0f / sig - 1.0f, 0.1f), 100.0f);

      float fh = fu * h3d;
      float d_ctr = fh / (fmaxf(p[42] - p[44], 0.f) * 4.f + 1e-6f);
      float d02 = 0.5f * (fh / (fmaxf(p[26] - p[34], 0.f) * 4.f + 1e-6f) +
                          fh / (fmaxf(p[30] - p[38], 0.f) * 4.f + 1e-6f));
      float d13 = 0.5f * (fh / (fmaxf(p[28] - p[36], 0.f) * 4.f + 1e-6f) +
                          fh / (fmaxf(p[32] - p[40], 0.f) * 4.f + 1e-6f));
      float kd0 = fminf(fmaxf(d_ctr, 0.1f), 100.f);
      float kd1 = fminf(fmaxf(d02, 0.1f), 100.f);
      float kd2 = fminf(fmaxf(d13, 0.1f), 100.f);

      float u0 = expf(p[49]), u1 = expf(p[45]), u2 = expf(p[46]), u3 = expf(p[47]);
      float w0 = 1.f / u0, w1 = 1.f / u1, w2 = 1.f / u2, w3 = 1.f / u3;
      float S = w0 + w1 + w2 + w3;
      float depth = (ddepth * w0 + kd0 * w1 + kd1 * w2 + kd2 * w3) / S;
      float derr = (w0 * u0 + w1 * u1 + w2 * u2 + w3 * u3) / S;

      float px = (x + p[4]) * 4.f - pad0;
      float py = (y + p[5]) * 4.f - pad1;
      float x3 = (px - cu) * depth / fu;
      float y3 = (py - cv) * depth / fv;

      orow[0] = (float)cls;
      orow[1] = score;
      orow[2] = bx0; orow[3] = by0; orow[4] = bx1; orow[5] = by1;
      orow[6] = d0;  orow[7] = d1;  orow[8] = d2;
      orow[9] = x3;  orow[10] = y3; orow[11] = depth;
      orow[12] = derr;
    }
  }
}

extern "C" void kernel_launch(void* const* d_in, const int* in_sizes, int n_in,
                              void* d_out, int out_size, void* d_ws, size_t ws_size,
                              hipStream_t stream) {
  const float* hmp   = (const float*)d_in[0];  // (16,3,96,320)
  const float* reg   = (const float*)d_in[1];  // (16,50,96,320)
  const float* calib = (const float*)d_in[2];  // (16,4)
  const float* pads  = (const float*)d_in[3];  // (16,2)
  const float* dm    = (const float*)d_in[4];  // (3,3)
  float* out = (float*)d_out;                  // 16*100*13 = 20800 floats

  unsigned long long* s1 = (unsigned long long*)d_ws;  // 48*100*8 = 38,400 B

  nms_topk<<<dim3(48), dim3(1024), 0, stream>>>(hmp, s1);
  merge_decode<<<dim3(16), dim3(256), 0, stream>>>(s1, reg, calib, pads, dm, out);
}

// Round 4
// 186.108 us; speedup vs baseline: 3.5881x; 1.0407x over previous
//
#include <hip/hip_runtime.h>
#include <math.h>

// MonoFlex post-processor for MI355X — round 4.
// B=16, NCLS=3, CREG=50, H=96, W=320, K=100, DOWN=4, THRESH=0.2
// out = (B*K, 13) f32 rows: [cls, score, box2d(4), dims(3), loc3d(3), depth_err]
//
// K1 nms_topk (48 blocks x 1024 thr): whole padded plane in LDS (126 KB).
//   - float2-vectorized NMS (9 ds_read_b64 per 4 elems vs 36 b32)
//   - candidates as u32 indices; cnt via wave-aggregated atomic (ballot)
//   - 1024-bin score histogram -> single-wave shfl suffix-scan -> rank-100
//     cutoff bin -> compact ~110 survivors -> bitonic-256 (fallback 1024)
//   key = (float_bits(score)<<32) | (0xFFFFFFFF - gi)  => desc == lax.top_k
// K2 merge_decode (16 blocks x 256): stage-2 re-key with pos tie-break
//   (== lax.top_k stage-2 stability), bitonic-512, 20-wide unrolled
//   100x50 gather, decode rows 0..99.
//
// ws use: 48*100*8 = 38,400 B only. NOTE (round 3 counters): the harness
// re-poisons the full preallocated d_ws (384 MB, ~59 us at 83% HBM peak) and
// restores inputs inside the timed region -> ~120 us floor independent of
// kernel time (round-2 calibration: dur 667.8 vs kernel 548.1).

#define W_ 320
#define H_ 96
#define HW_ (W_ * H_)
#define LDSW 322   // even -> every row base stays 8B-aligned for float2 reads
#define LDSH 98
#define CANDCAP 4096
#define BITS_02 0x3E4CCCCDu  // float bits of 0.2f

__global__ __launch_bounds__(1024) void nms_topk(
    const float* __restrict__ hmp,
    unsigned long long* __restrict__ s1) {
  const int plane = blockIdx.x;  // 0..47 = b*3 + cls
  const int t = threadIdx.x;     // 0..1023
  const int lane = t & 63;
  const float* p = hmp + (size_t)plane * HW_;

  __shared__ float lp[LDSH * LDSW];          // 126,224 B padded plane
  __shared__ unsigned cand[CANDCAP];         // 16,384 B candidate indices
  __shared__ unsigned long long skey[1024];  // 8,192 B sort keys
  __shared__ int hist[1024];                 // 4,096 B
  __shared__ int cnt, mcnt, cutbin;

  if (t == 0) { cnt = 0; mcnt = 0; cutbin = 0; }
  hist[t] = 0;

  // halo-only -inf init (interior is fully overwritten by staging)
  if (t < 836) {
    int idx;
    if (t < 322)      idx = t;                           // row 0
    else if (t < 644) idx = 97 * LDSW + (t - 322);       // row 97
    else if (t < 740) idx = (t - 644 + 1) * LDSW;        // col 0, rows 1..96
    else              idx = (t - 740 + 1) * LDSW + 321;  // col 321, rows 1..96
    lp[idx] = -INFINITY;
  }

  // stage plane with float4 loads (rows are 80 float4s, no row-crossing)
  const float4* p4 = (const float4*)p;
  for (int i = t; i < HW_ / 4; i += 1024) {
    float4 v = p4[i];
    int gi0 = i << 2;
    int row = gi0 / W_;
    int col = gi0 - row * W_;
    float* d = &lp[(row + 1) * LDSW + col + 1];
    d[0] = v.x; d[1] = v.y; d[2] = v.z; d[3] = v.w;
  }
  __syncthreads();

  // NMS: each item = 4 consecutive elems; window cols [c..c+5] per row,
  // all float2-aligned (row base even, c multiple of 4).
  for (int i = t; i < HW_ / 4; i += 1024) {
    int r = i / 80;               // 0..95
    int c4 = (i - r * 80) << 2;   // 0,4,...,316
    const float2* w0 = (const float2*)&lp[r * LDSW + c4];
    const float2* w1 = (const float2*)&lp[(r + 1) * LDSW + c4];
    const float2* w2 = (const float2*)&lp[(r + 2) * LDSW + c4];
    float2 a0 = w0[0], a1 = w0[1], a2 = w0[2];
    float2 b0 = w1[0], b1 = w1[1], b2 = w1[2];
    float2 e0 = w2[0], e1 = w2[1], e2 = w2[2];
    float t0[6] = {a0.x, a0.y, a1.x, a1.y, a2.x, a2.y};
    float t1[6] = {b0.x, b0.y, b1.x, b1.y, b2.x, b2.y};
    float t2[6] = {e0.x, e0.y, e1.x, e1.y, e2.x, e2.y};
    #pragma unroll
    for (int j = 0; j < 4; ++j) {
      float v = t1[j + 1];
      bool pass = (v >= -1.3865f) &&  // margin below logit(0.2); exact test next
                  (v >= t0[j]) && (v >= t0[j + 1]) && (v >= t0[j + 2]) &&
                  (v >= t1[j]) && (v >= t1[j + 2]) &&
                  (v >= t2[j]) && (v >= t2[j + 1]) && (v >= t2[j + 2]);
      if (pass) {
        float s = 1.0f / (1.0f + expf(-v));
        pass = (s >= 0.2f);  // exact reference-matching threshold
        if (pass) {
          unsigned bits = __float_as_uint(s);
          unsigned bin = (bits - BITS_02) >> 15;
          if (bin > 1023u) bin = 1023u;
          atomicAdd(&hist[bin], 1);
        }
      }
      unsigned long long act = __ballot(pass);
      if (pass) {
        unsigned gi = (unsigned)(r * W_ + c4 + j);
        int rank = __popcll(act & ((1ull << lane) - 1));
        int base;
        if (rank == 0) base = atomicAdd(&cnt, (int)__popcll(act));
        base = __shfl(base, (int)__ffsll(act) - 1);
        int q = base + rank;
        if (q < CANDCAP) cand[q] = gi;
      }
    }
  }
  __syncthreads();

  // single-wave suffix scan over 1024 bins -> rank-100 cutoff bin
  if (t < 64) {
    int ssum = 0;
    #pragma unroll
    for (int k2 = 0; k2 < 16; ++k2) ssum += hist[t * 16 + k2];
    int suf = ssum;
    #pragma unroll
    for (int off = 1; off < 64; off <<= 1) {
      int o = __shfl_down(suf, off);
      if (lane + off < 64) suf += o;
    }
    int sufn = __shfl_down(suf, 1);
    if (lane == 63) sufn = 0;
    if (suf >= 100 && sufn < 100) {  // exactly one lane (if total >= 100)
      int acc = sufn;
      int cb = t * 16;
      for (int k2 = t * 16 + 15; k2 >= t * 16; --k2) {
        acc += hist[k2];
        if (acc >= 100) { cb = k2; break; }
      }
      cutbin = cb;
    }
  }
  __syncthreads();
  const int cb = cutbin;
  const int n = min(cnt, CANDCAP);

  // compact survivors (~110), recomputing score from the resident plane
  for (int i = t; i < n; i += 1024) {
    unsigned gi = cand[i];
    int row = (int)gi / W_;
    int col = (int)gi - row * W_;
    float v = lp[(row + 1) * LDSW + col + 1];
    float s = 1.0f / (1.0f + expf(-v));
    unsigned bits = __float_as_uint(s);
    unsigned bin = (bits - BITS_02) >> 15;
    if (bin > 1023u) bin = 1023u;
    if ((int)bin >= cb) {
      int q = atomicAdd(&mcnt, 1);
      if (q < 1024)
        skey[q] = ((unsigned long long)bits << 32) |
                  (unsigned long long)(0xFFFFFFFFu - gi);
    }
  }
  __syncthreads();
  const int m = min(mcnt, 1024);
  const int N = (m <= 256) ? 256 : 1024;  // uniform across block
  if (t < N && t >= m) skey[t] = 0ULL;
  __syncthreads();

  // bitonic sort descending over N slots (keys unique -> deterministic)
  for (int k = 2; k <= N; k <<= 1) {
    for (int j = k >> 1; j > 0; j >>= 1) {
      if (t < N) {
        int l = t ^ j;
        if (l > t) {
          unsigned long long a = skey[t], b2 = skey[l];
          if ((a > b2) == ((t & k) != 0)) { skey[t] = b2; skey[l] = a; }
        }
      }
      __syncthreads();
    }
  }
  if (t < 100) s1[plane * 100 + t] = skey[t];
}

__global__ __launch_bounds__(256) void merge_decode(
    const unsigned long long* __restrict__ s1,
    const float* __restrict__ reg,
    const float* __restrict__ calib,
    const float* __restrict__ pad_size,
    const float* __restrict__ dim_mean,
    float* __restrict__ out) {
  const int b = blockIdx.x;   // 0..15
  const int t = threadIdx.x;  // 0..255

  __shared__ unsigned long long topk[300];
  __shared__ unsigned long long keys[512];
  __shared__ int selgi[100];
  __shared__ int selcls[100];
  __shared__ float selsc[100];
  __shared__ float pbuf[100 * 51];  // stride 51 to spread banks

  for (int i = t; i < 300; i += 256) topk[i] = s1[b * 300 + i];
  __syncthreads();
  for (int i = t; i < 512; i += 256) {
    unsigned long long kk = 0ULL;
    if (i < 300) {
      unsigned bits = (unsigned)(topk[i] >> 32);
      if (bits != 0u)
        kk = ((unsigned long long)bits << 32) |
             (unsigned long long)(0xFFFFFFFFu - (unsigned)i);
    }
    keys[i] = kk;
  }
  __syncthreads();
  // bitonic desc, N=512; tie-break = lower pos300 (class asc, rank asc)
  for (int k = 2; k <= 512; k <<= 1) {
    for (int j = k >> 1; j > 0; j >>= 1) {
      for (int i = t; i < 512; i += 256) {
        int l = i ^ j;
        if (l > i) {
          unsigned long long a = keys[i], b2 = keys[l];
          if ((a > b2) == ((i & k) != 0)) { keys[i] = b2; keys[l] = a; }
        }
      }
      __syncthreads();
    }
  }

  if (t < 100) {
    unsigned long long key = keys[t];
    float score = __uint_as_float((unsigned)(key >> 32));
    if (score >= 0.2f) {
      unsigned pos = 0xFFFFFFFFu - (unsigned)(key & 0xFFFFFFFFull);  // < 300
      selcls[t] = (int)(pos / 100u);
      unsigned long long e = topk[pos];
      selgi[t] = (int)(0xFFFFFFFFu - (unsigned)(e & 0xFFFFFFFFull));
      selsc[t] = score;
    } else {
      selgi[t] = -1;
      selcls[t] = 0;
      selsc[t] = 0.0f;
    }
  }
  __syncthreads();

  // cooperative gather: 100 rows x 50 channels, fully unrolled so all 20
  // global loads per thread are in flight together.
  const float* rbase = reg + (size_t)b * 50 * HW_;
  float gv[20];
  int gidx[20];
  #pragma unroll
  for (int rr = 0; rr < 20; ++rr) {
    int idx = rr * 256 + t;
    bool ok = idx < 5000;
    int row = ok ? (idx % 100) : 0;
    int ch  = ok ? (idx / 100) : 0;
    int gi = selgi[row];
    gv[rr] = (ok && gi >= 0) ? rbase[(size_t)ch * HW_ + gi] : 0.0f;
    gidx[rr] = row * 51 + ch;
  }
  #pragma unroll
  for (int rr = 0; rr < 20; ++rr) {
    int idx = rr * 256 + t;
    if (idx < 5000) pbuf[gidx[rr]] = gv[rr];
  }
  __syncthreads();

  if (t < 100) {
    float* orow = out + ((size_t)b * 100 + t) * 13;
    int gi = selgi[t];
    if (gi < 0) {
      #pragma unroll
      for (int i = 0; i < 13; ++i) orow[i] = 0.0f;
    } else {
      const float* p = &pbuf[t * 51];
      int cls = selcls[t];
      float score = selsc[t];
      int yy = gi / W_;
      int xx = gi - yy * W_;
      float x = (float)xx, y = (float)yy;

      float fu = calib[b * 4 + 0], cu = calib[b * 4 + 1];
      float fv = calib[b * 4 + 2], cv = calib[b * 4 + 3];
      float pad0 = pad_size[b * 2 + 0], pad1 = pad_size[b * 2 + 1];

      float r0 = fmaxf(p[0], 0.f), r1 = fmaxf(p[1], 0.f);
      float r2 = fmaxf(p[2], 0.f), r3 = fmaxf(p[3], 0.f);
      float bx0 = fminf(fmaxf((x - r0) * 4.f - pad0, 0.f), 1279.f);
      float by0 = fminf(fmaxf((y - r1) * 4.f - pad1, 0.f), 383.f);
      float bx1 = fminf(fmaxf((x + r2) * 4.f - pad0, 0.f), 1279.f);
      float by1 = fminf(fmaxf((y + r3) * 4.f - pad1, 0.f), 383.f);

      float d0 = expf(p[6]) * dim_mean[cls * 3 + 0];
      float d1 = expf(p[7]) * dim_mean[cls * 3 + 1];
      float d2 = expf(p[8]) * dim_mean[cls * 3 + 2];
      float h3d = d1;

      float sig = 1.0f / (1.0f + expf(-p[48]));
      float ddepth = fminf(fmaxf(1.0f / sig - 1.0f, 0.1f), 100.0f);

      float fh = fu * h3d;
      float d_ctr = fh / (fmaxf(p[42] - p[44], 0.f) * 4.f + 1e-6f);
      float d02 = 0.5f * (fh / (fmaxf(p[26] - p[34], 0.f) * 4.f + 1e-6f) +
                          fh / (fmaxf(p[30] - p[38], 0.f) * 4.f + 1e-6f));
      float d13 = 0.5f * (fh / (fmaxf(p[28] - p[36], 0.f) * 4.f + 1e-6f) +
                          fh / (fmaxf(p[32] - p[40], 0.f) * 4.f + 1e-6f));
      float kd0 = fminf(fmaxf(d_ctr, 0.1f), 100.f);
      float kd1 = fminf(fmaxf(d02, 0.1f), 100.f);
      float kd2 = fminf(fmaxf(d13, 0.1f), 100.f);

      float u0 = expf(p[49]), u1 = expf(p[45]), u2 = expf(p[46]), u3 = expf(p[47]);
      float w0 = 1.f / u0, w1 = 1.f / u1, w2 = 1.f / u2, w3 = 1.f / u3;
      float S = w0 + w1 + w2 + w3;
      float depth = (ddepth * w0 + kd0 * w1 + kd1 * w2 + kd2 * w3) / S;
      float derr = (w0 * u0 + w1 * u1 + w2 * u2 + w3 * u3) / S;

      float px = (x + p[4]) * 4.f - pad0;
      float py = (y + p[5]) * 4.f - pad1;
      float x3 = (px - cu) * depth / fu;
      float y3 = (py - cv) * depth / fv;

      orow[0] = (float)cls;
      orow[1] = score;
      orow[2] = bx0; orow[3] = by0; orow[4] = bx1; orow[5] = by1;
      orow[6] = d0;  orow[7] = d1;  orow[8] = d2;
      orow[9] = x3;  orow[10] = y3; orow[11] = depth;
      orow[12] = derr;
    }
  }
}

extern "C" void kernel_launch(void* const* d_in, const int* in_sizes, int n_in,
                              void* d_out, int out_size, void* d_ws, size_t ws_size,
                              hipStream_t stream) {
  const float* hmp   = (const float*)d_in[0];  // (16,3,96,320)
  const float* reg   = (const float*)d_in[1];  // (16,50,96,320)
  const float* calib = (const float*)d_in[2];  // (16,4)
  const float* pads  = (const float*)d_in[3];  // (16,2)
  const float* dm    = (const float*)d_in[4];  // (3,3)
  float* out = (float*)d_out;                  // 16*100*13 = 20800 floats

  unsigned long long* s1 = (unsigned long long*)d_ws;  // 48*100*8 = 38,400 B

  nms_topk<<<dim3(48), dim3(1024), 0, stream>>>(hmp, s1);
  merge_decode<<<dim3(16), dim3(256), 0, stream>>>(s1, reg, calib, pads, dm, out);
}

// Round 5
// 184.250 us; speedup vs baseline: 3.6243x; 1.0101x over previous
//
#include <hip/hip_runtime.h>
#include <math.h>

// MonoFlex post-processor for MI355X — round 5: single fused launch.
// B=16, NCLS=3, CREG=50, H=96, W=320, K=100, DOWN=4, THRESH=0.2
// out = (B*K, 13) f32 rows: [cls, score, box2d(4), dims(3), loc3d(3), depth_err]
//
// 48 blocks x 1024 thr, one per (b,cls) plane:
//   stage plane to LDS (scalar dword: coalesced global, stride-1 LDS writes)
//   NMS via separable max: vertical 3-max per column (stride-1 b32, conflict-
//   free) + horizontal combine via __shfl (320%64==0 -> wave == row segment;
//   edge lanes patch from LDS). pass <=> v >= max9 <=> hmax==heat.
//   candidates -> 1024-bin hist -> wave suffix-scan rank-100 cutoff ->
//   compact -> bitonic sort (N in {128,256,1024}) -> top-100 keys.
//   key = (float_bits(score)<<32) | (0xFFFFFFFF - gi)  => desc == lax.top_k.
//   Publish to ws s1 + flag (threadfence + device atomicExch).
// cls==0 blocks then merge their batch: spin on 2 sibling flags (atomicCAS),
//   atomic-load sibling keys (bypasses non-coherent L2s), merged rank via
//   binary search (bits desc, class asc, rank asc == stage-2 lax.top_k
//   stability), cooperative 100x50 gather, decode.
//
// ws: s1 48*100*8 = 38400 B + flags 48*4 B. Harness poisons ws to 0xAA before
// every call (clears flags; 384 MB fill = ~58us of the ~120us fixed floor).
// Stale-flag hazard is benign anyway: s1 is identical on every call.
// Round-4 lesson: any layout where one thread owns 4 consecutive columns has
// 16B inter-lane stride = 8-way LDS bank conflict (2.94x, m136). Keep all
// LDS access lane-stride-1.

#define W_ 320
#define H_ 96
#define HW_ (W_ * H_)
#define LDSW 322
#define LDSH 98
#define CANDCAP 4096
#define BITS_02 0x3E4CCCCDu     // float bits of 0.2f
#define FLAG_MAGIC 0x5EC0DE01

__global__ __launch_bounds__(1024) void monoflex_all(
    const float* __restrict__ hmp,
    const float* __restrict__ reg,
    const float* __restrict__ calib,
    const float* __restrict__ pad_size,
    const float* __restrict__ dim_mean,
    float* __restrict__ out,
    unsigned long long* __restrict__ s1,
    int* __restrict__ flags) {
  const int plane = blockIdx.x;  // 0..47 = b*3 + cls
  const int b = plane / 3;
  const int cls0 = plane - b * 3;
  const int t = threadIdx.x;     // 0..1023
  const int lane = t & 63;
  const float* p = hmp + (size_t)plane * HW_;

  __shared__ __align__(16) float lp[LDSH * LDSW];  // 126,224 B
  __shared__ unsigned cand[CANDCAP];               // 16,384 B
  __shared__ unsigned long long skey[1024];        // 8,192 B
  __shared__ int hist[1024];                       // 4,096 B
  __shared__ int cnt, mcnt, cutbin;

  if (t == 0) { cnt = 0; mcnt = 0; cutbin = 0; }
  hist[t] = 0;

  // halo-only -inf init (interior fully overwritten by staging)
  if (t < 836) {
    int idx;
    if (t < 322)      idx = t;                           // row 0
    else if (t < 644) idx = 97 * LDSW + (t - 322);       // row 97
    else if (t < 740) idx = (t - 644 + 1) * LDSW;        // col 0, rows 1..96
    else              idx = (t - 740 + 1) * LDSW + 321;  // col 321, rows 1..96
    lp[idx] = -INFINITY;
  }

  // stage: scalar dword (256B/wave coalesced global; stride-1 LDS writes)
  for (int i = t; i < HW_; i += 1024) {
    float v = p[i];
    int r = i / W_;
    int col = i - r * W_;
    lp[(r + 1) * LDSW + col + 1] = v;
  }
  __syncthreads();

  // NMS: separable max. Each wave covers 64 consecutive cols of one row.
  for (int i = t; i < HW_; i += 1024) {
    int r = i / W_;               // 0..95
    int c = i - r * W_;           // 0..319, lane-consecutive
    int cc = c + 1;               // padded col
    float a = lp[r * LDSW + cc];
    float v = lp[(r + 1) * LDSW + cc];
    float e = lp[(r + 2) * LDSW + cc];
    float vm = fmaxf(fmaxf(a, v), e);
    float vmL = __shfl_up(vm, 1);
    float vmR = __shfl_down(vm, 1);
    if (lane == 0)
      vmL = fmaxf(fmaxf(lp[r * LDSW + cc - 1], lp[(r + 1) * LDSW + cc - 1]),
                  lp[(r + 2) * LDSW + cc - 1]);
    if (lane == 63)
      vmR = fmaxf(fmaxf(lp[r * LDSW + cc + 1], lp[(r + 1) * LDSW + cc + 1]),
                  lp[(r + 2) * LDSW + cc + 1]);
    float m9 = fmaxf(fmaxf(vmL, vm), vmR);
    bool pass = (v >= m9);  // == (hmax == heat) for this cell
    if (pass) {
      float s = 1.0f / (1.0f + expf(-v));
      pass = (s >= 0.2f);  // exact reference threshold
      if (pass) {
        unsigned bits = __float_as_uint(s);
        unsigned bin = (bits - BITS_02) >> 15;
        if (bin > 1023u) bin = 1023u;
        atomicAdd(&hist[bin], 1);
      }
    }
    unsigned long long act = __ballot(pass);
    if (pass) {
      int rank = __popcll(act & ((1ull << lane) - 1));
      int base;
      if (rank == 0) base = atomicAdd(&cnt, (int)__popcll(act));
      base = __shfl(base, (int)__ffsll(act) - 1);
      int q = base + rank;
      if (q < CANDCAP) cand[q] = (unsigned)i;
    }
  }
  __syncthreads();

  // single-wave suffix scan over 1024 bins -> rank-100 cutoff bin
  if (t < 64) {
    int ssum = 0;
    #pragma unroll
    for (int k2 = 0; k2 < 16; ++k2) ssum += hist[t * 16 + k2];
    int suf = ssum;
    #pragma unroll
    for (int off = 1; off < 64; off <<= 1) {
      int o = __shfl_down(suf, off);
      if (lane + off < 64) suf += o;
    }
    int sufn = __shfl_down(suf, 1);
    if (lane == 63) sufn = 0;
    if (suf >= 100 && sufn < 100) {
      int acc = sufn;
      int cb = t * 16;
      for (int k2 = t * 16 + 15; k2 >= t * 16; --k2) {
        acc += hist[k2];
        if (acc >= 100) { cb = k2; break; }
      }
      cutbin = cb;
    }
  }
  __syncthreads();
  const int cb = cutbin;
  const int n = min(cnt, CANDCAP);

  // compact survivors (~105), recomputing score from resident plane
  for (int i = t; i < n; i += 1024) {
    unsigned gi = cand[i];
    int row = (int)gi / W_;
    int col = (int)gi - row * W_;
    float v = lp[(row + 1) * LDSW + col + 1];
    float s = 1.0f / (1.0f + expf(-v));
    unsigned bits = __float_as_uint(s);
    unsigned bin = (bits - BITS_02) >> 15;
    if (bin > 1023u) bin = 1023u;
    if ((int)bin >= cb) {
      int q = atomicAdd(&mcnt, 1);
      if (q < 1024)
        skey[q] = ((unsigned long long)bits << 32) |
                  (unsigned long long)(0xFFFFFFFFu - gi);
    }
  }
  __syncthreads();
  const int m = min(mcnt, 1024);
  const int N = (m <= 128) ? 128 : ((m <= 256) ? 256 : 1024);
  if (t < N && t >= m) skey[t] = 0ULL;
  __syncthreads();

  // bitonic sort descending over N slots (keys unique -> deterministic)
  for (int k = 2; k <= N; k <<= 1) {
    for (int j = k >> 1; j > 0; j >>= 1) {
      if (t < N) {
        int l = t ^ j;
        if (l > t) {
          unsigned long long a = skey[t], b2 = skey[l];
          if ((a > b2) == ((t & k) != 0)) { skey[t] = b2; skey[l] = a; }
        }
      }
      __syncthreads();
    }
  }

  // publish top-100 + flag (store -> fence -> barrier -> device atomic)
  if (t < 100) s1[plane * 100 + t] = skey[t];
  __threadfence();
  __syncthreads();
  if (t == 0) atomicExch(&flags[plane], FLAG_MAGIC);
  if (cls0 != 0) return;

  // ================= merge phase (16 cls==0 blocks) =================
  // LDS overlays into lp (dead after compact); skey still live (own top-100).
  unsigned long long* topk = (unsigned long long*)lp;  // [0,300) -> 2400 B
  int*   selgi  = (int*)(lp + 600);
  int*   selcls = (int*)(lp + 700);
  float* selsc  = (float*)(lp + 800);
  float* pbuf   = lp + 900;  // 100 x 51 floats

  if (t < 100) topk[t] = skey[t];
  if (t == 0)
    while (atomicCAS(&flags[plane + 1], FLAG_MAGIC, FLAG_MAGIC) != FLAG_MAGIC) {}
  if (t == 64)
    while (atomicCAS(&flags[plane + 2], FLAG_MAGIC, FLAG_MAGIC) != FLAG_MAGIC) {}
  __syncthreads();
  // sibling keys via atomic loads (coherence-point reads, no stale L1/L2)
  if (t >= 100 && t < 300) topk[t] = atomicAdd(&s1[b * 300 + t], 0ULL);
  __syncthreads();

  // merged rank of each of the 300 entries; comparator = bits desc, then
  // class asc, then within-class rank asc (== stage-2 lax.top_k stability)
  if (t < 300) {
    int c2 = t / 100, r2 = t - c2 * 100;
    unsigned long long key = topk[t];
    unsigned bits = (unsigned)(key >> 32);
    int rank = r2;
    #pragma unroll
    for (int cp = 0; cp < 3; ++cp) {
      if (cp == c2) continue;
      const unsigned long long* L = topk + cp * 100;
      int lo = 0, hi = 100;
      while (lo < hi) {  // first idx with bits_i <= bits  -> cntGT
        int mid = (lo + hi) >> 1;
        if ((unsigned)(L[mid] >> 32) > bits) lo = mid + 1; else hi = mid;
      }
      int cntGT = lo;
      if (cp < c2) {
        lo = cntGT; hi = 100;
        while (lo < hi) {  // first idx with bits_i < bits -> cntGE
          int mid = (lo + hi) >> 1;
          if ((unsigned)(L[mid] >> 32) >= bits) lo = mid + 1; else hi = mid;
        }
        rank += lo;        // cntGT + cntEQ
      } else {
        rank += cntGT;
      }
    }
    if (rank < 100) {
      bool valid = (bits != 0u);
      selgi[rank]  = valid ? (int)(0xFFFFFFFFu - (unsigned)(key & 0xFFFFFFFFull))
                           : -1;
      selcls[rank] = c2;
      selsc[rank]  = __uint_as_float(bits);
    }
  }
  __syncthreads();

  // cooperative gather: 100 rows x 50 channels, 5 in-flight loads/thread
  const float* rbase = reg + (size_t)b * 50 * HW_;
  {
    float gv[5];
    int gx[5];
    #pragma unroll
    for (int rr = 0; rr < 5; ++rr) {
      int idx = rr * 1024 + t;
      bool ok = idx < 5000;
      int row = ok ? (idx % 100) : 0;
      int ch  = ok ? (idx / 100) : 0;
      int gi = selgi[row];
      gv[rr] = (ok && gi >= 0) ? rbase[(size_t)ch * HW_ + gi] : 0.0f;
      gx[rr] = row * 51 + ch;
    }
    #pragma unroll
    for (int rr = 0; rr < 5; ++rr) {
      int idx = rr * 1024 + t;
      if (idx < 5000) pbuf[gx[rr]] = gv[rr];
    }
  }
  __syncthreads();

  if (t < 100) {
    float* orow = out + ((size_t)b * 100 + t) * 13;
    int gi = selgi[t];
    if (gi < 0) {
      #pragma unroll
      for (int i = 0; i < 13; ++i) orow[i] = 0.0f;
    } else {
      const float* pp = &pbuf[t * 51];
      int cls = selcls[t];
      float score = selsc[t];
      int yy = gi / W_;
      int xx = gi - yy * W_;
      float x = (float)xx, y = (float)yy;

      float fu = calib[b * 4 + 0], cu = calib[b * 4 + 1];
      float fv = calib[b * 4 + 2], cv = calib[b * 4 + 3];
      float pad0 = pad_size[b * 2 + 0], pad1 = pad_size[b * 2 + 1];

      float r0 = fmaxf(pp[0], 0.f), r1 = fmaxf(pp[1], 0.f);
      float r2 = fmaxf(pp[2], 0.f), r3 = fmaxf(pp[3], 0.f);
      float bx0 = fminf(fmaxf((x - r0) * 4.f - pad0, 0.f), 1279.f);
      float by0 = fminf(fmaxf((y - r1) * 4.f - pad1, 0.f), 383.f);
      float bx1 = fminf(fmaxf((x + r2) * 4.f - pad0, 0.f), 1279.f);
      float by1 = fminf(fmaxf((y + r3) * 4.f - pad1, 0.f), 383.f);

      float d0 = expf(pp[6]) * dim_mean[cls * 3 + 0];
      float d1 = expf(pp[7]) * dim_mean[cls * 3 + 1];
      float d2 = expf(pp[8]) * dim_mean[cls * 3 + 2];
      float h3d = d1;

      float sig = 1.0f / (1.0f + expf(-pp[48]));
      float ddepth = fminf(fmaxf(1.0f / sig - 1.0f, 0.1f), 100.0f);

      float fh = fu * h3d;
      float d_ctr = fh / (fmaxf(pp[42] - pp[44], 0.f) * 4.f + 1e-6f);
      float d02 = 0.5f * (fh / (fmaxf(pp[26] - pp[34], 0.f) * 4.f + 1e-6f) +
                          fh / (fmaxf(pp[30] - pp[38], 0.f) * 4.f + 1e-6f));
      float d13 = 0.5f * (fh / (fmaxf(pp[28] - pp[36], 0.f) * 4.f + 1e-6f) +
                          fh / (fmaxf(pp[32] - pp[40], 0.f) * 4.f + 1e-6f));
      float kd0 = fminf(fmaxf(d_ctr, 0.1f), 100.f);
      float kd1 = fminf(fmaxf(d02, 0.1f), 100.f);
      float kd2 = fminf(fmaxf(d13, 0.1f), 100.f);

      float u0 = expf(pp[49]), u1 = expf(pp[45]);
      float u2 = expf(pp[46]), u3 = expf(pp[47]);
      float w0 = 1.f / u0, w1 = 1.f / u1, w2 = 1.f / u2, w3 = 1.f / u3;
      float S = w0 + w1 + w2 + w3;
      float depth = (ddepth * w0 + kd0 * w1 + kd1 * w2 + kd2 * w3) / S;
      float derr = (w0 * u0 + w1 * u1 + w2 * u2 + w3 * u3) / S;

      float px = (x + pp[4]) * 4.f - pad0;
      float py = (y + pp[5]) * 4.f - pad1;
      float x3 = (px - cu) * depth / fu;
      float y3 = (py - cv) * depth / fv;

      orow[0] = (float)cls;
      orow[1] = score;
      orow[2] = bx0; orow[3] = by0; orow[4] = bx1; orow[5] = by1;
      orow[6] = d0;  orow[7] = d1;  orow[8] = d2;
      orow[9] = x3;  orow[10] = y3; orow[11] = depth;
      orow[12] = derr;
    }
  }
}

extern "C" void kernel_launch(void* const* d_in, const int* in_sizes, int n_in,
                              void* d_out, int out_size, void* d_ws, size_t ws_size,
                              hipStream_t stream) {
  const float* hmp   = (const float*)d_in[0];  // (16,3,96,320)
  const float* reg   = (const float*)d_in[1];  // (16,50,96,320)
  const float* calib = (const float*)d_in[2];  // (16,4)
  const float* pads  = (const float*)d_in[3];  // (16,2)
  const float* dm    = (const float*)d_in[4];  // (3,3)
  float* out = (float*)d_out;                  // 16*100*13 = 20800 floats

  unsigned long long* s1 = (unsigned long long*)d_ws;  // 38,400 B
  int* flags = (int*)((char*)d_ws + 48 * 100 * 8);     // +192 B

  monoflex_all<<<dim3(48), dim3(1024), 0, stream>>>(hmp, reg, calib, pads, dm,
                                                    out, s1, flags);
}

// Round 6
// 173.049 us; speedup vs baseline: 3.8589x; 1.0647x over previous
//
#include <hip/hip_runtime.h>
#include <math.h>

// MonoFlex post-processor for MI355X — round 6: 96-block fused, global-direct NMS.
// B=16, NCLS=3, CREG=50, H=96, W=320, K=100, DOWN=4, THRESH=0.2
// out = (B*K, 13) f32 rows: [cls, score, box2d(4), dims(3), loc3d(3), depth_err]
//
// Grid: 96 blocks x 1024 thr; block ph = b*6 + cls*2 + half (half = 48 rows).
//   NMS straight from global (up/center/down coalesced loads; horizontal via
//   __shfl with edge-lane patch loads; out-of-plane = -inf like 'SAME' pad).
//   pass <=> v >= max9 (== hmax==heat) and sigmoid >= 0.2.
//   Candidates = full keys (float_bits(score)<<32)|(~gi)  => desc == lax.top_k
//   (score desc, flat-index asc). 1024-bin hist -> single-wave suffix scan ->
//   rank-100 cutoff -> compact (~110) -> TOP-128 SORT IN ONE WAVE (2 elems/
//   lane, shfl_xor bitonic, zero barriers; block-wide bitonic-256/512 fallback
//   if m>128) -> publish sorted 100 keys + device flag.
// Merge (the 16 ph%6==0 blocks): spin 5 sibling flags, atomic-load 600 keys,
//   merge-1 per class (rank = own + cntGT(other half) on full keys -> exact
//   per-class top-100), then round-5's verified stage-2 (bits desc, class asc,
//   rank asc == lax.top_k stage-2 stability), 100x50 gather, decode.
//
// ws: s1 96*100*8 = 76.8 KB + flags 384 B. Harness re-poisons full ws (384 MB
// fill, ~58 us) + restores inputs every timed call: fixed ~124 us floor
// (dur 184.25 - kernel 60.6 in round 5). Kernel-side is all that's left.
// Round-4 lesson kept: all LDS/lane access patterns stride-1.

#define W_ 320
#define H_ 96
#define HW_ (W_ * H_)
#define CANDCAP 2048
#define SKEYCAP 512
#define BITS_02 0x3E4CCCCDu     // float bits of 0.2f
#define FLAG_MAGIC 0x5EC0DE01

__device__ inline unsigned long long shflx64(unsigned long long v, int m) {
  int lo = __shfl_xor((int)(unsigned)v, m, 64);
  int hi = __shfl_xor((int)(unsigned)(v >> 32), m, 64);
  return ((unsigned long long)(unsigned)hi << 32) | (unsigned)lo;
}

__global__ __launch_bounds__(1024) void monoflex_all(
    const float* __restrict__ hmp,
    const float* __restrict__ reg,
    const float* __restrict__ calib,
    const float* __restrict__ pad_size,
    const float* __restrict__ dim_mean,
    float* __restrict__ out,
    unsigned long long* __restrict__ s1,
    int* __restrict__ flags) {
  const int ph = blockIdx.x;        // 0..95 = b*6 + cls*2 + half
  const int half = ph & 1;
  const int plane = ph >> 1;        // b*3 + cls
  const int t = threadIdx.x;        // 0..1023
  const int lane = t & 63;
  const float* p = hmp + (size_t)plane * HW_;
  const int r0 = half * 48;

  __shared__ unsigned long long cand[CANDCAP];   // 16,384 B full keys
  __shared__ unsigned long long skey[SKEYCAP];   //  4,096 B
  __shared__ int hist[1024];                     //  4,096 B
  __shared__ int cnt, mcnt, cutbin;
  // merge-phase arrays (static union is fine; ~53 KB total)
  __shared__ unsigned long long halfkeys[600];   //  4,800 B
  __shared__ unsigned long long classlist[300];  //  2,400 B
  __shared__ int selgi[100];
  __shared__ int selcls[100];
  __shared__ float selsc[100];
  __shared__ float pbuf[100 * 51];               // 20,400 B

  if (t == 0) { cnt = 0; mcnt = 0; cutbin = 0; }
  hist[t] = 0;
  __syncthreads();

  // ---- NMS straight from global: 15 iters, lane-consecutive columns ----
  for (int idx = t; idx < 48 * W_; idx += 1024) {
    int rr = idx / W_;
    int c = idx - rr * W_;
    int r = r0 + rr;
    int g = r * W_ + c;
    float v = p[g];
    float up = (r > 0) ? p[g - W_] : -INFINITY;
    float dn = (r < 95) ? p[g + W_] : -INFINITY;
    float vm = fmaxf(fmaxf(up, dn), v);
    float vmL = __shfl_up(vm, 1);
    float vmR = __shfl_down(vm, 1);
    if (lane == 0) {
      vmL = -INFINITY;
      if (c > 0) {
        float lv = p[g - 1];
        float lu = (r > 0) ? p[g - W_ - 1] : -INFINITY;
        float ld = (r < 95) ? p[g + W_ - 1] : -INFINITY;
        vmL = fmaxf(fmaxf(lu, ld), lv);
      }
    }
    if (lane == 63) {
      vmR = -INFINITY;
      if (c < 319) {
        float rv = p[g + 1];
        float ru = (r > 0) ? p[g - W_ + 1] : -INFINITY;
        float rd = (r < 95) ? p[g + W_ + 1] : -INFINITY;
        vmR = fmaxf(fmaxf(ru, rd), rv);
      }
    }
    float m9 = fmaxf(fmaxf(vmL, vmR), vm);
    bool pass = (v >= m9) && (v > -1.3865f);  // margin below logit(0.2)
    unsigned bits = 0u;
    if (pass) {
      float s = 1.0f / (1.0f + expf(-v));
      pass = (s >= 0.2f);  // exact reference threshold
      if (pass) {
        bits = __float_as_uint(s);
        unsigned bin = (bits - BITS_02) >> 15;
        if (bin > 1023u) bin = 1023u;
        atomicAdd(&hist[bin], 1);
      }
    }
    unsigned long long act = __ballot(pass);
    if (pass) {
      int rank = __popcll(act & ((1ull << lane) - 1));
      int base;
      if (rank == 0) base = atomicAdd(&cnt, (int)__popcll(act));
      base = __shfl(base, (int)__ffsll(act) - 1);
      int q = base + rank;
      if (q < CANDCAP)
        cand[q] = ((unsigned long long)bits << 32) |
                  (unsigned long long)(0xFFFFFFFFu - (unsigned)g);
    }
  }
  __syncthreads();

  // ---- single-wave suffix scan over 1024 bins -> rank-100 cutoff ----
  if (t < 64) {
    int ssum = 0;
    #pragma unroll
    for (int k2 = 0; k2 < 16; ++k2) ssum += hist[t * 16 + k2];
    int suf = ssum;
    #pragma unroll
    for (int off = 1; off < 64; off <<= 1) {
      int o = __shfl_down(suf, off);
      if (lane + off < 64) suf += o;
    }
    int sufn = __shfl_down(suf, 1);
    if (lane == 63) sufn = 0;
    if (suf >= 100 && sufn < 100) {
      int acc = sufn;
      int cb = t * 16;
      for (int k2 = t * 16 + 15; k2 >= t * 16; --k2) {
        acc += hist[k2];
        if (acc >= 100) { cb = k2; break; }
      }
      cutbin = cb;
    }
  }
  __syncthreads();
  const int cb = cutbin;
  const int n = min(cnt, CANDCAP);

  // ---- compact survivors (~110) ----
  for (int i = t; i < n; i += 1024) {
    unsigned long long k = cand[i];
    unsigned bin = ((unsigned)(k >> 32) - BITS_02) >> 15;
    if (bin > 1023u) bin = 1023u;
    if ((int)bin >= cb) {
      int q = atomicAdd(&mcnt, 1);
      if (q < SKEYCAP) skey[q] = k;
    }
  }
  __syncthreads();
  const int m = min(mcnt, SKEYCAP);
  if (t >= m && t < SKEYCAP) skey[t] = 0ULL;
  __syncthreads();

  unsigned long long* dst = s1 + (size_t)ph * 100;
  if (m <= 128) {
    // ---- top-128 bitonic in ONE wave, 2 elems/lane, zero barriers ----
    if (t < 64) {
      unsigned long long e0 = skey[lane], e1 = skey[64 + lane];
      #pragma unroll
      for (int k = 2; k <= 128; k <<= 1) {
        #pragma unroll
        for (int j = k >> 1; j > 0; j >>= 1) {
          if (j == 64) {  // k==128 only; asc=false for all i<128
            if (e0 <= e1) { unsigned long long tmp = e0; e0 = e1; e1 = tmp; }
          } else {
            bool lower = ((lane & j) == 0);
            {
              unsigned long long o = shflx64(e0, j);
              bool asc = ((lane & k) != 0);
              unsigned long long lv = lower ? e0 : o, uv = lower ? o : e0;
              if ((lv > uv) == asc) e0 = o;
            }
            {
              unsigned long long o = shflx64(e1, j);
              bool asc = (((64 + lane) & k) != 0);
              unsigned long long lv = lower ? e1 : o, uv = lower ? o : e1;
              if ((lv > uv) == asc) e1 = o;
            }
          }
        }
      }
      dst[lane] = e0;                       // ranks 0..63
      if (lane < 36) dst[64 + lane] = e1;   // ranks 64..99
      __threadfence();
      if (lane == 0) atomicExch(&flags[ph], FLAG_MAGIC);
    }
  } else {
    // ---- fallback: block-wide bitonic over N in {256,512} ----
    const int N = (m <= 256) ? 256 : 512;
    for (int k = 2; k <= N; k <<= 1) {
      for (int j = k >> 1; j > 0; j >>= 1) {
        if (t < N) {
          int l = t ^ j;
          if (l > t) {
            unsigned long long a = skey[t], b2 = skey[l];
            if ((a > b2) == ((t & k) != 0)) { skey[t] = b2; skey[l] = a; }
          }
        }
        __syncthreads();
      }
    }
    if (t < 100) dst[t] = skey[t];
    __threadfence();
    __syncthreads();
    if (t == 0) atomicExch(&flags[ph], FLAG_MAGIC);
  }

  if ((ph % 6) != 0) return;

  // ================= merge phase (16 blocks, ph = b*6) =================
  const int b = ph / 6;
  if (t < 5)
    while (atomicCAS(&flags[ph + 1 + t], FLAG_MAGIC, FLAG_MAGIC) != FLAG_MAGIC) {}
  __syncthreads();
  // 600 keys via coherence-point reads (bypass non-coherent L1/L2)
  if (t < 600) halfkeys[t] = atomicAdd(&s1[b * 600 + t], 0ULL);
  if (t < 300) classlist[t] = 0ULL;
  __syncthreads();

  // merge-1: per class, rank = own_rank + cntGT(other half) on full keys
  if (t < 600) {
    int c2 = t / 200, h = (t / 100) & 1, r = t % 100;
    unsigned long long key = halfkeys[t];
    if (key != 0ULL) {
      const unsigned long long* L = &halfkeys[(c2 * 2 + (1 - h)) * 100];
      int lo = 0, hi = 100;
      while (lo < hi) {
        int mid = (lo + hi) >> 1;
        if (L[mid] > key) lo = mid + 1; else hi = mid;
      }
      int cr = r + lo;
      if (cr < 100) classlist[c2 * 100 + cr] = key;
    }
  }
  __syncthreads();

  // stage-2 (round-5 verified): bits desc, class asc, rank asc == lax.top_k
  if (t < 300) {
    int c2 = t / 100, r2 = t - c2 * 100;
    unsigned long long key = classlist[t];
    unsigned bits = (unsigned)(key >> 32);
    int rank = r2;
    #pragma unroll
    for (int cp = 0; cp < 3; ++cp) {
      if (cp == c2) continue;
      const unsigned long long* L = classlist + cp * 100;
      int lo = 0, hi = 100;
      while (lo < hi) {  // first idx with bits_i <= bits -> cntGT
        int mid = (lo + hi) >> 1;
        if ((unsigned)(L[mid] >> 32) > bits) lo = mid + 1; else hi = mid;
      }
      int cntGT = lo;
      if (cp < c2) {
        lo = cntGT; hi = 100;
        while (lo < hi) {  // first idx with bits_i < bits -> cntGE
          int mid = (lo + hi) >> 1;
          if ((unsigned)(L[mid] >> 32) >= bits) lo = mid + 1; else hi = mid;
        }
        rank += lo;        // cntGT + cntEQ
      } else {
        rank += cntGT;
      }
    }
    if (rank < 100) {
      bool valid = (bits != 0u);
      selgi[rank]  = valid ? (int)(0xFFFFFFFFu - (unsigned)(key & 0xFFFFFFFFull))
                           : -1;
      selcls[rank] = c2;
      selsc[rank]  = __uint_as_float(bits);
    }
  }
  __syncthreads();

  // cooperative gather: 100 rows x 50 channels, 5 in-flight loads/thread
  const float* rbase = reg + (size_t)b * 50 * HW_;
  {
    float gv[5];
    int gx[5];
    #pragma unroll
    for (int rr2 = 0; rr2 < 5; ++rr2) {
      int idx = rr2 * 1024 + t;
      bool ok = idx < 5000;
      int row = ok ? (idx % 100) : 0;
      int ch  = ok ? (idx / 100) : 0;
      int gi = selgi[row];
      gv[rr2] = (ok && gi >= 0) ? rbase[(size_t)ch * HW_ + gi] : 0.0f;
      gx[rr2] = row * 51 + ch;
    }
    #pragma unroll
    for (int rr2 = 0; rr2 < 5; ++rr2) {
      int idx = rr2 * 1024 + t;
      if (idx < 5000) pbuf[gx[rr2]] = gv[rr2];
    }
  }
  __syncthreads();

  if (t < 100) {
    float* orow = out + ((size_t)b * 100 + t) * 13;
    int gi = selgi[t];
    if (gi < 0) {
      #pragma unroll
      for (int i = 0; i < 13; ++i) orow[i] = 0.0f;
    } else {
      const float* pp = &pbuf[t * 51];
      int cls = selcls[t];
      float score = selsc[t];
      int yy = gi / W_;
      int xx = gi - yy * W_;
      float x = (float)xx, y = (float)yy;

      float fu = calib[b * 4 + 0], cu = calib[b * 4 + 1];
      float fv = calib[b * 4 + 2], cv = calib[b * 4 + 3];
      float pad0 = pad_size[b * 2 + 0], pad1 = pad_size[b * 2 + 1];

      float rA = fmaxf(pp[0], 0.f), rB = fmaxf(pp[1], 0.f);
      float rC = fmaxf(pp[2], 0.f), rD = fmaxf(pp[3], 0.f);
      float bx0 = fminf(fmaxf((x - rA) * 4.f - pad0, 0.f), 1279.f);
      float by0 = fminf(fmaxf((y - rB) * 4.f - pad1, 0.f), 383.f);
      float bx1 = fminf(fmaxf((x + rC) * 4.f - pad0, 0.f), 1279.f);
      float by1 = fminf(fmaxf((y + rD) * 4.f - pad1, 0.f), 383.f);

      float d0 = expf(pp[6]) * dim_mean[cls * 3 + 0];
      float d1 = expf(pp[7]) * dim_mean[cls * 3 + 1];
      float d2 = expf(pp[8]) * dim_mean[cls * 3 + 2];
      float h3d = d1;

      float sig = 1.0f / (1.0f + expf(-pp[48]));
      float ddepth = fminf(fmaxf(1.0f / sig - 1.0f, 0.1f), 100.0f);

      float fh = fu * h3d;
      float d_ctr = fh / (fmaxf(pp[42] - pp[44], 0.f) * 4.f + 1e-6f);
      float d02 = 0.5f * (fh / (fmaxf(pp[26] - pp[34], 0.f) * 4.f + 1e-6f) +
                          fh / (fmaxf(pp[30] - pp[38], 0.f) * 4.f + 1e-6f));
      float d13 = 0.5f * (fh / (fmaxf(pp[28] - pp[36], 0.f) * 4.f + 1e-6f) +
                          fh / (fmaxf(pp[32] - pp[40], 0.f) * 4.f + 1e-6f));
      float kd0 = fminf(fmaxf(d_ctr, 0.1f), 100.f);
      float kd1 = fminf(fmaxf(d02, 0.1f), 100.f);
      float kd2 = fminf(fmaxf(d13, 0.1f), 100.f);

      float u0 = expf(pp[49]), u1 = expf(pp[45]);
      float u2 = expf(pp[46]), u3 = expf(pp[47]);
      float w0 = 1.f / u0, w1 = 1.f / u1, w2 = 1.f / u2, w3 = 1.f / u3;
      float S = w0 + w1 + w2 + w3;
      float depth = (ddepth * w0 + kd0 * w1 + kd1 * w2 + kd2 * w3) / S;
      float derr = (w0 * u0 + w1 * u1 + w2 * u2 + w3 * u3) / S;

      float px = (x + pp[4]) * 4.f - pad0;
      float py = (y + pp[5]) * 4.f - pad1;
      float x3 = (px - cu) * depth / fu;
      float y3 = (py - cv) * depth / fv;

      orow[0] = (float)cls;
      orow[1] = score;
      orow[2] = bx0; orow[3] = by0; orow[4] = bx1; orow[5] = by1;
      orow[6] = d0;  orow[7] = d1;  orow[8] = d2;
      orow[9] = x3;  orow[10] = y3; orow[11] = depth;
      orow[12] = derr;
    }
  }
}

extern "C" void kernel_launch(void* const* d_in, const int* in_sizes, int n_in,
                              void* d_out, int out_size, void* d_ws, size_t ws_size,
                              hipStream_t stream) {
  const float* hmp   = (const float*)d_in[0];  // (16,3,96,320)
  const float* reg   = (const float*)d_in[1];  // (16,50,96,320)
  const float* calib = (const float*)d_in[2];  // (16,4)
  const float* pads  = (const float*)d_in[3];  // (16,2)
  const float* dm    = (const float*)d_in[4];  // (3,3)
  float* out = (float*)d_out;                  // 16*100*13 = 20800 floats

  unsigned long long* s1 = (unsigned long long*)d_ws;  // 96*100*8 = 76,800 B
  int* flags = (int*)((char*)d_ws + 96 * 100 * 8);     // +384 B

  monoflex_all<<<dim3(96), dim3(1024), 0, stream>>>(hmp, reg, calib, pads, dm,
                                                    out, s1, flags);
}

// Round 8
// 169.214 us; speedup vs baseline: 3.9463x; 1.0227x over previous
//
#include <hip/hip_runtime.h>
#include <math.h>

// MonoFlex post-processor for MI355X — round 8: round-7 structure, fan-in fixed.
// B=16, NCLS=3, CREG=50, H=96, W=320, K=100, DOWN=4, THRESH=0.2
// out = (B*K, 13) f32 rows: [cls, score, box2d(4), dims(3), loc3d(3), depth_err]
//
// K1 nms_topk: 192 blocks x 1024 thr; block = plane*4 + quarter (24 rows).
//   NMS straight from global (coalesced up/center/down; horizontal via __shfl
//   with edge-lane patches; out-of-plane = -inf == 'SAME' pad semantics).
//   pass <=> v >= max9 (== hmax==heat) and sigmoid(v) >= 0.2.
//   key = (float_bits(score)<<32)|(0xFFFFFFFF-gi) => desc sort == lax.top_k
//   (score desc, flat idx asc). 1024-bin hist -> single-wave suffix scan ->
//   rank-100 cutoff -> compact (~105) -> one-wave top-128 bitonic (2 elems/
//   lane, shfl_xor, zero barriers; block bitonic-256/512 fallback) -> 100
//   sorted keys to ws. No flags/fences: kernel boundary = coherence point.
// K2 merge_decode: 16 blocks x 1024. Merge-4 per class over ALL 1200 entries
//   (ROUND-7 BUG: `if (t<1200)` with 1024 threads left entries 1024..1199
//   unmerged -> holes in "sorted" lists -> uninit selgi -> wild global read
//   -> HSA abort. Now a grid-stride loop + selgi pre-init to -1.)
//   rank = own rank + sum cntGT(sibling quarters) on full unique keys ->
//   exact per-class top-100. Then stage-2 (bits desc, class asc, rank asc ==
//   lax.top_k stage-2 stability), cooperative 100x50 gather, decode.
//
// ws: s1 = 192*100*8 = 153,600 B (ws_size ~384 MB per the harness's own
// poison fill). Fixed harness floor ~121 us (384 MB ws fill ~58 us at 85%
// HBM peak + input restores + gaps) — untouchable from kernel code.
// Round-4 lesson kept: lane-consecutive (stride-1) access everywhere.

#define W_ 320
#define H_ 96
#define HW_ (W_ * H_)
#define QROWS 24
#define CANDCAP 2048
#define SKEYCAP 512
#define BITS_02 0x3E4CCCCDu     // float bits of 0.2f

__device__ inline unsigned long long shflx64(unsigned long long v, int m) {
  int lo = __shfl_xor((int)(unsigned)v, m, 64);
  int hi = __shfl_xor((int)(unsigned)(v >> 32), m, 64);
  return ((unsigned long long)(unsigned)hi << 32) | (unsigned)lo;
}

__global__ __launch_bounds__(1024) void nms_topk(
    const float* __restrict__ hmp,
    unsigned long long* __restrict__ s1) {
  const int ph = blockIdx.x;        // 0..191 = plane*4 + q
  const int plane = ph >> 2;        // b*3 + cls
  const int q = ph & 3;
  const int r0 = q * QROWS;
  const int t = threadIdx.x;        // 0..1023
  const int lane = t & 63;
  const float* p = hmp + (size_t)plane * HW_;

  __shared__ unsigned long long cand[CANDCAP];   // 16,384 B full keys
  __shared__ unsigned long long skey[SKEYCAP];   //  4,096 B
  __shared__ int hist[1024];                     //  4,096 B
  __shared__ int cnt, mcnt, cutbin;

  if (t == 0) { cnt = 0; mcnt = 0; cutbin = 0; }
  hist[t] = 0;
  __syncthreads();

  // ---- NMS from global: 7.5 iters, lane-consecutive columns ----
  // (last iteration covers threads 0..511 only = waves 0..7, full waves)
  for (int idx = t; idx < QROWS * W_; idx += 1024) {
    int rr = idx / W_;
    int c = idx - rr * W_;
    int r = r0 + rr;
    int g = r * W_ + c;
    float v = p[g];
    float up = (r > 0) ? p[g - W_] : -INFINITY;
    float dn = (r < 95) ? p[g + W_] : -INFINITY;
    float vm = fmaxf(fmaxf(up, dn), v);
    float vmL = __shfl_up(vm, 1);
    float vmR = __shfl_down(vm, 1);
    if (lane == 0) {
      vmL = -INFINITY;
      if (c > 0) {
        float lv = p[g - 1];
        float lu = (r > 0) ? p[g - W_ - 1] : -INFINITY;
        float ld = (r < 95) ? p[g + W_ - 1] : -INFINITY;
        vmL = fmaxf(fmaxf(lu, ld), lv);
      }
    }
    if (lane == 63) {
      vmR = -INFINITY;
      if (c < 319) {
        float rv = p[g + 1];
        float ru = (r > 0) ? p[g - W_ + 1] : -INFINITY;
        float rd = (r < 95) ? p[g + W_ + 1] : -INFINITY;
        vmR = fmaxf(fmaxf(ru, rd), rv);
      }
    }
    float m9 = fmaxf(fmaxf(vmL, vmR), vm);
    bool pass = (v >= m9) && (v > -1.3865f);  // margin below logit(0.2)
    unsigned bits = 0u;
    if (pass) {
      float s = 1.0f / (1.0f + expf(-v));
      pass = (s >= 0.2f);  // exact reference threshold
      if (pass) {
        bits = __float_as_uint(s);
        unsigned bin = (bits - BITS_02) >> 15;
        if (bin > 1023u) bin = 1023u;
        atomicAdd(&hist[bin], 1);
      }
    }
    unsigned long long act = __ballot(pass);
    if (pass) {
      int rank = __popcll(act & ((1ull << lane) - 1));
      int base;
      if (rank == 0) base = atomicAdd(&cnt, (int)__popcll(act));
      base = __shfl(base, (int)__ffsll(act) - 1);
      int qq = base + rank;
      if (qq < CANDCAP)
        cand[qq] = ((unsigned long long)bits << 32) |
                   (unsigned long long)(0xFFFFFFFFu - (unsigned)g);
    }
  }
  __syncthreads();

  // ---- single-wave suffix scan over 1024 bins -> rank-100 cutoff ----
  if (t < 64) {
    int ssum = 0;
    #pragma unroll
    for (int k2 = 0; k2 < 16; ++k2) ssum += hist[t * 16 + k2];
    int suf = ssum;
    #pragma unroll
    for (int off = 1; off < 64; off <<= 1) {
      int o = __shfl_down(suf, off);
      if (lane + off < 64) suf += o;
    }
    int sufn = __shfl_down(suf, 1);
    if (lane == 63) sufn = 0;
    if (suf >= 100 && sufn < 100) {
      int acc = sufn;
      int cb = t * 16;
      for (int k2 = t * 16 + 15; k2 >= t * 16; --k2) {
        acc += hist[k2];
        if (acc >= 100) { cb = k2; break; }
      }
      cutbin = cb;
    }
  }
  __syncthreads();
  const int cb = cutbin;
  const int n = min(cnt, CANDCAP);

  // ---- compact survivors (~105) ----
  for (int i = t; i < n; i += 1024) {
    unsigned long long k = cand[i];
    unsigned bin = ((unsigned)(k >> 32) - BITS_02) >> 15;
    if (bin > 1023u) bin = 1023u;
    if ((int)bin >= cb) {
      int qq = atomicAdd(&mcnt, 1);
      if (qq < SKEYCAP) skey[qq] = k;
    }
  }
  __syncthreads();
  const int m = min(mcnt, SKEYCAP);
  if (t >= m && t < SKEYCAP) skey[t] = 0ULL;
  __syncthreads();

  unsigned long long* dst = s1 + (size_t)ph * 100;
  if (m <= 128) {
    // one-wave top-128 bitonic, 2 elems/lane, zero barriers (HW-verified R6)
    if (t < 64) {
      unsigned long long e0 = skey[lane], e1 = skey[64 + lane];
      #pragma unroll
      for (int k = 2; k <= 128; k <<= 1) {
        #pragma unroll
        for (int j = k >> 1; j > 0; j >>= 1) {
          if (j == 64) {  // k==128 only; desc for all i<128
            if (e0 <= e1) { unsigned long long tmp = e0; e0 = e1; e1 = tmp; }
          } else {
            bool lower = ((lane & j) == 0);
            {
              unsigned long long o = shflx64(e0, j);
              bool asc = ((lane & k) != 0);
              unsigned long long lv = lower ? e0 : o, uv = lower ? o : e0;
              if ((lv > uv) == asc) e0 = o;
            }
            {
              unsigned long long o = shflx64(e1, j);
              bool asc = (((64 + lane) & k) != 0);
              unsigned long long lv = lower ? e1 : o, uv = lower ? o : e1;
              if ((lv > uv) == asc) e1 = o;
            }
          }
        }
      }
      dst[lane] = e0;                       // ranks 0..63
      if (lane < 36) dst[64 + lane] = e1;   // ranks 64..99
    }
  } else {
    const int N = (m <= 256) ? 256 : 512;
    for (int k = 2; k <= N; k <<= 1) {
      for (int j = k >> 1; j > 0; j >>= 1) {
        if (t < N) {
          int l = t ^ j;
          if (l > t) {
            unsigned long long a = skey[t], b2 = skey[l];
            if ((a > b2) == ((t & k) != 0)) { skey[t] = b2; skey[l] = a; }
          }
        }
        __syncthreads();
      }
    }
    if (t < 100) dst[t] = skey[t];
  }
}

__global__ __launch_bounds__(1024) void merge_decode(
    const unsigned long long* __restrict__ s1,
    const float* __restrict__ reg,
    const float* __restrict__ calib,
    const float* __restrict__ pad_size,
    const float* __restrict__ dim_mean,
    float* __restrict__ out) {
  const int b = blockIdx.x;   // 0..15
  const int t = threadIdx.x;  // 0..1023

  __shared__ unsigned long long qkeys[1200];     // 12 quarter-lists
  __shared__ unsigned long long classlist[300];
  __shared__ int selgi[100];
  __shared__ int selcls[100];
  __shared__ float selsc[100];
  __shared__ float pbuf[100 * 51];

  for (int i = t; i < 1200; i += 1024) qkeys[i] = s1[b * 1200 + i];
  if (t < 300) classlist[t] = 0ULL;
  if (t < 100) { selgi[t] = -1; selcls[t] = 0; selsc[t] = 0.0f; }  // R7 fix
  __syncthreads();

  // merge-4 per class over ALL 1200 entries (R7 fix: grid-stride loop, not
  // `if (t < 1200)` with only 1024 threads): rank = own rank + sum
  // cntGT(sibling quarter) on full unique keys -> exact per-class top-100.
  for (int i = t; i < 1200; i += 1024) {
    int c2 = i / 400;          // class
    int qo = (i / 100) & 3;    // own quarter
    int r = i % 100;
    unsigned long long key = qkeys[i];
    if (key != 0ULL) {
      int rank = r;
      #pragma unroll
      for (int qs = 0; qs < 4; ++qs) {
        if (qs == qo) continue;
        const unsigned long long* L = &qkeys[(c2 * 4 + qs) * 100];
        int lo = 0, hi = 100;
        while (lo < hi) {  // first idx with L[mid] <= key -> cntGT
          int mid = (lo + hi) >> 1;
          if (L[mid] > key) lo = mid + 1; else hi = mid;
        }
        rank += lo;
      }
      if (rank < 100) classlist[c2 * 100 + rank] = key;
    }
  }
  __syncthreads();

  // stage-2 (HW-verified R5/R6): bits desc, class asc, rank asc
  if (t < 300) {
    int c2 = t / 100, r2 = t - c2 * 100;
    unsigned long long key = classlist[t];
    unsigned bits = (unsigned)(key >> 32);
    int rank = r2;
    #pragma unroll
    for (int cp = 0; cp < 3; ++cp) {
      if (cp == c2) continue;
      const unsigned long long* L = classlist + cp * 100;
      int lo = 0, hi = 100;
      while (lo < hi) {  // first idx with bits_i <= bits -> cntGT
        int mid = (lo + hi) >> 1;
        if ((unsigned)(L[mid] >> 32) > bits) lo = mid + 1; else hi = mid;
      }
      int cntGT = lo;
      if (cp < c2) {
        lo = cntGT; hi = 100;
        while (lo < hi) {  // first idx with bits_i < bits -> cntGE
          int mid = (lo + hi) >> 1;
          if ((unsigned)(L[mid] >> 32) >= bits) lo = mid + 1; else hi = mid;
        }
        rank += lo;        // cntGT + cntEQ
      } else {
        rank += cntGT;
      }
    }
    if (rank < 100 && bits != 0u) {
      selgi[rank]  = (int)(0xFFFFFFFFu - (unsigned)(key & 0xFFFFFFFFull));
      selcls[rank] = c2;
      selsc[rank]  = __uint_as_float(bits);
    }
  }
  __syncthreads();

  // cooperative gather: 100 rows x 50 channels, 5 in-flight loads/thread
  const float* rbase = reg + (size_t)b * 50 * HW_;
  {
    float gv[5];
    int gx[5];
    #pragma unroll
    for (int rr2 = 0; rr2 < 5; ++rr2) {
      int idx = rr2 * 1024 + t;
      bool ok = idx < 5000;
      int row = ok ? (idx % 100) : 0;
      int ch  = ok ? (idx / 100) : 0;
      int gi = selgi[row];
      gv[rr2] = (ok && gi >= 0) ? rbase[(size_t)ch * HW_ + gi] : 0.0f;
      gx[rr2] = row * 51 + ch;
    }
    #pragma unroll
    for (int rr2 = 0; rr2 < 5; ++rr2) {
      int idx = rr2 * 1024 + t;
      if (idx < 5000) pbuf[gx[rr2]] = gv[rr2];
    }
  }
  __syncthreads();

  if (t < 100) {
    float* orow = out + ((size_t)b * 100 + t) * 13;
    int gi = selgi[t];
    if (gi < 0) {
      #pragma unroll
      for (int i = 0; i < 13; ++i) orow[i] = 0.0f;
    } else {
      const float* pp = &pbuf[t * 51];
      int cls = selcls[t];
      float score = selsc[t];
      int yy = gi / W_;
      int xx = gi - yy * W_;
      float x = (float)xx, y = (float)yy;

      float fu = calib[b * 4 + 0], cu = calib[b * 4 + 1];
      float fv = calib[b * 4 + 2], cv = calib[b * 4 + 3];
      float pad0 = pad_size[b * 2 + 0], pad1 = pad_size[b * 2 + 1];

      float rA = fmaxf(pp[0], 0.f), rB = fmaxf(pp[1], 0.f);
      float rC = fmaxf(pp[2], 0.f), rD = fmaxf(pp[3], 0.f);
      float bx0 = fminf(fmaxf((x - rA) * 4.f - pad0, 0.f), 1279.f);
      float by0 = fminf(fmaxf((y - rB) * 4.f - pad1, 0.f), 383.f);
      float bx1 = fminf(fmaxf((x + rC) * 4.f - pad0, 0.f), 1279.f);
      float by1 = fminf(fmaxf((y + rD) * 4.f - pad1, 0.f), 383.f);

      float d0 = expf(pp[6]) * dim_mean[cls * 3 + 0];
      float d1 = expf(pp[7]) * dim_mean[cls * 3 + 1];
      float d2 = expf(pp[8]) * dim_mean[cls * 3 + 2];
      float h3d = d1;

      float sig = 1.0f / (1.0f + expf(-pp[48]));
      float ddepth = fminf(fmaxf(1.0f / sig - 1.0f, 0.1f), 100.0f);

      float fh = fu * h3d;
      float d_ctr = fh / (fmaxf(pp[42] - pp[44], 0.f) * 4.f + 1e-6f);
      float d02 = 0.5f * (fh / (fmaxf(pp[26] - pp[34], 0.f) * 4.f + 1e-6f) +
                          fh / (fmaxf(pp[30] - pp[38], 0.f) * 4.f + 1e-6f));
      float d13 = 0.5f * (fh / (fmaxf(pp[28] - pp[36], 0.f) * 4.f + 1e-6f) +
                          fh / (fmaxf(pp[32] - pp[40], 0.f) * 4.f + 1e-6f));
      float kd0 = fminf(fmaxf(d_ctr, 0.1f), 100.f);
      float kd1 = fminf(fmaxf(d02, 0.1f), 100.f);
      float kd2 = fminf(fmaxf(d13, 0.1f), 100.f);

      float u0 = expf(pp[49]), u1 = expf(pp[45]);
      float u2 = expf(pp[46]), u3 = expf(pp[47]);
      float w0 = 1.f / u0, w1 = 1.f / u1, w2 = 1.f / u2, w3 = 1.f / u3;
      float S = w0 + w1 + w2 + w3;
      float depth = (ddepth * w0 + kd0 * w1 + kd1 * w2 + kd2 * w3) / S;
      float derr = (w0 * u0 + w1 * u1 + w2 * u2 + w3 * u3) / S;

      float px = (x + pp[4]) * 4.f - pad0;
      float py = (y + pp[5]) * 4.f - pad1;
      float x3 = (px - cu) * depth / fu;
      float y3 = (py - cv) * depth / fv;

      orow[0] = (float)cls;
      orow[1] = score;
      orow[2] = bx0; orow[3] = by0; orow[4] = bx1; orow[5] = by1;
      orow[6] = d0;  orow[7] = d1;  orow[8] = d2;
      orow[9] = x3;  orow[10] = y3; orow[11] = depth;
      orow[12] = derr;
    }
  }
}

extern "C" void kernel_launch(void* const* d_in, const int* in_sizes, int n_in,
                              void* d_out, int out_size, void* d_ws, size_t ws_size,
                              hipStream_t stream) {
  const float* hmp   = (const float*)d_in[0];  // (16,3,96,320)
  const float* reg   = (const float*)d_in[1];  // (16,50,96,320)
  const float* calib = (const float*)d_in[2];  // (16,4)
  const float* pads  = (const float*)d_in[3];  // (16,2)
  const float* dm    = (const float*)d_in[4];  // (3,3)
  float* out = (float*)d_out;                  // 16*100*13 = 20800 floats

  unsigned long long* s1 = (unsigned long long*)d_ws;  // 192*100*8 = 153,600 B

  nms_topk<<<dim3(192), dim3(1024), 0, stream>>>(hmp, s1);
  merge_decode<<<dim3(16), dim3(1024), 0, stream>>>(s1, reg, calib, pads, dm, out);
}

// Round 9
// 167.211 us; speedup vs baseline: 3.9936x; 1.0120x over previous
//
#include <hip/hip_runtime.h>
#include <math.h>

// MonoFlex post-processor for MI355X — round 9: single 208-block launch.
// B=16, NCLS=3, CREG=50, H=96, W=320, K=100, DOWN=4, THRESH=0.2
// out = (B*K, 13) f32 rows: [cls, score, box2d(4), dims(3), loc3d(3), depth_err]
//
// Blocks 0..191 (= plane*4 + quarter, 24 rows each): R8-verified NMS pipeline
//   straight from global (coalesced up/center/down; horizontal via __shfl with
//   edge-lane patches; out-of-plane = -inf == 'SAME' pad). pass <=> v >= max9
//   and sigmoid(v) >= 0.2. key = (bits(score)<<32)|(~gi) => desc == lax.top_k.
//   1024-bin hist -> single-wave suffix scan -> rank-100 cutoff -> compact ->
//   one-wave top-128 bitonic (block 256/512 fallback) -> publish 100 sorted
//   keys + threadfence + device-scope flag (R5/R6-verified pattern).
// Blocks 192..207 (one per batch): spin 12 flags (atomicCAS + s_sleep),
//   atomic-load 1200 keys (coherence-point reads, XCD-safe), merge-4 per
//   class over ALL 1200 entries (grid-stride; R7 bug fixed in R8), stage-2
//   (bits desc, class asc, rank asc == lax.top_k stage-2 stability),
//   cooperative 100x50 gather, decode. selgi pre-init -1 (defense in depth).
//
// 208 blocks x 1024 thr, ~58 KB LDS -> 1 block/CU, all co-resident (same
// spin-fan-in regime HW-verified in R5/R6 at 48/96 blocks).
// ws: s1 192*100*8 = 153,600 B + flags 192*4 B. Harness poisons ws to 0xAA
// each replay (flags reset; fills+restores = fixed ~122 us floor, calibrated
// R2: 667.8-548.1 and R5: 184.3-60.7). R8 kernel-side ~47 us is dominated by
// per-launch constants (gaps/ramp/DVFS), so this round removes one launch.
// Round-4 lesson kept: lane-consecutive (stride-1) access everywhere.

#define W_ 320
#define H_ 96
#define HW_ (W_ * H_)
#define QROWS 24
#define CANDCAP 2048
#define SKEYCAP 512
#define BITS_02 0x3E4CCCCDu     // float bits of 0.2f
#define FLAG_MAGIC 0x5EC0DE01

__device__ inline unsigned long long shflx64(unsigned long long v, int m) {
  int lo = __shfl_xor((int)(unsigned)v, m, 64);
  int hi = __shfl_xor((int)(unsigned)(v >> 32), m, 64);
  return ((unsigned long long)(unsigned)hi << 32) | (unsigned)lo;
}

__global__ __launch_bounds__(1024) void monoflex_all(
    const float* __restrict__ hmp,
    const float* __restrict__ reg,
    const float* __restrict__ calib,
    const float* __restrict__ pad_size,
    const float* __restrict__ dim_mean,
    float* __restrict__ out,
    unsigned long long* s1,
    int* flags) {
  const int blk = blockIdx.x;       // 0..207
  const int t = threadIdx.x;        // 0..1023
  const int lane = t & 63;

  if (blk < 192) {
    // ================= NMS blocks (R8-verified) =================
    const int ph = blk;             // plane*4 + q
    const int plane = ph >> 2;      // b*3 + cls
    const int q = ph & 3;
    const int r0 = q * QROWS;
    const float* p = hmp + (size_t)plane * HW_;

    __shared__ unsigned long long cand[CANDCAP];   // 16,384 B full keys
    __shared__ unsigned long long skey[SKEYCAP];   //  4,096 B
    __shared__ int hist[1024];                     //  4,096 B
    __shared__ int cnt, mcnt, cutbin;

    if (t == 0) { cnt = 0; mcnt = 0; cutbin = 0; }
    hist[t] = 0;
    __syncthreads();

    // NMS from global: 7.5 iters, lane-consecutive columns
    for (int idx = t; idx < QROWS * W_; idx += 1024) {
      int rr = idx / W_;
      int c = idx - rr * W_;
      int r = r0 + rr;
      int g = r * W_ + c;
      float v = p[g];
      float up = (r > 0) ? p[g - W_] : -INFINITY;
      float dn = (r < 95) ? p[g + W_] : -INFINITY;
      float vm = fmaxf(fmaxf(up, dn), v);
      float vmL = __shfl_up(vm, 1);
      float vmR = __shfl_down(vm, 1);
      if (lane == 0) {
        vmL = -INFINITY;
        if (c > 0) {
          float lv = p[g - 1];
          float lu = (r > 0) ? p[g - W_ - 1] : -INFINITY;
          float ld = (r < 95) ? p[g + W_ - 1] : -INFINITY;
          vmL = fmaxf(fmaxf(lu, ld), lv);
        }
      }
      if (lane == 63) {
        vmR = -INFINITY;
        if (c < 319) {
          float rv = p[g + 1];
          float ru = (r > 0) ? p[g - W_ + 1] : -INFINITY;
          float rd = (r < 95) ? p[g + W_ + 1] : -INFINITY;
          vmR = fmaxf(fmaxf(ru, rd), rv);
        }
      }
      float m9 = fmaxf(fmaxf(vmL, vmR), vm);
      bool pass = (v >= m9) && (v > -1.3865f);  // margin below logit(0.2)
      unsigned bits = 0u;
      if (pass) {
        float s = 1.0f / (1.0f + expf(-v));
        pass = (s >= 0.2f);  // exact reference threshold
        if (pass) {
          bits = __float_as_uint(s);
          unsigned bin = (bits - BITS_02) >> 15;
          if (bin > 1023u) bin = 1023u;
          atomicAdd(&hist[bin], 1);
        }
      }
      unsigned long long act = __ballot(pass);
      if (pass) {
        int rank = __popcll(act & ((1ull << lane) - 1));
        int base;
        if (rank == 0) base = atomicAdd(&cnt, (int)__popcll(act));
        base = __shfl(base, (int)__ffsll(act) - 1);
        int qq = base + rank;
        if (qq < CANDCAP)
          cand[qq] = ((unsigned long long)bits << 32) |
                     (unsigned long long)(0xFFFFFFFFu - (unsigned)g);
      }
    }
    __syncthreads();

    // single-wave suffix scan over 1024 bins -> rank-100 cutoff
    if (t < 64) {
      int ssum = 0;
      #pragma unroll
      for (int k2 = 0; k2 < 16; ++k2) ssum += hist[t * 16 + k2];
      int suf = ssum;
      #pragma unroll
      for (int off = 1; off < 64; off <<= 1) {
        int o = __shfl_down(suf, off);
        if (lane + off < 64) suf += o;
      }
      int sufn = __shfl_down(suf, 1);
      if (lane == 63) sufn = 0;
      if (suf >= 100 && sufn < 100) {
        int acc = sufn;
        int cb = t * 16;
        for (int k2 = t * 16 + 15; k2 >= t * 16; --k2) {
          acc += hist[k2];
          if (acc >= 100) { cb = k2; break; }
        }
        cutbin = cb;
      }
    }
    __syncthreads();
    const int cb = cutbin;
    const int n = min(cnt, CANDCAP);

    // compact survivors (~105)
    for (int i = t; i < n; i += 1024) {
      unsigned long long k = cand[i];
      unsigned bin = ((unsigned)(k >> 32) - BITS_02) >> 15;
      if (bin > 1023u) bin = 1023u;
      if ((int)bin >= cb) {
        int qq = atomicAdd(&mcnt, 1);
        if (qq < SKEYCAP) skey[qq] = k;
      }
    }
    __syncthreads();
    const int m = min(mcnt, SKEYCAP);
    if (t >= m && t < SKEYCAP) skey[t] = 0ULL;
    __syncthreads();

    unsigned long long* dst = s1 + (size_t)ph * 100;
    if (m <= 128) {
      // one-wave top-128 bitonic, 2 elems/lane, zero barriers (R6-verified)
      if (t < 64) {
        unsigned long long e0 = skey[lane], e1 = skey[64 + lane];
        #pragma unroll
        for (int k = 2; k <= 128; k <<= 1) {
          #pragma unroll
          for (int j = k >> 1; j > 0; j >>= 1) {
            if (j == 64) {  // k==128 only; desc for all i<128
              if (e0 <= e1) { unsigned long long tmp = e0; e0 = e1; e1 = tmp; }
            } else {
              bool lower = ((lane & j) == 0);
              {
                unsigned long long o = shflx64(e0, j);
                bool asc = ((lane & k) != 0);
                unsigned long long lv = lower ? e0 : o, uv = lower ? o : e0;
                if ((lv > uv) == asc) e0 = o;
              }
              {
                unsigned long long o = shflx64(e1, j);
                bool asc = (((64 + lane) & k) != 0);
                unsigned long long lv = lower ? e1 : o, uv = lower ? o : e1;
                if ((lv > uv) == asc) e1 = o;
              }
            }
          }
        }
        dst[lane] = e0;                       // ranks 0..63
        if (lane < 36) dst[64 + lane] = e1;   // ranks 64..99
        __threadfence();
        if (lane == 0) atomicExch(&flags[ph], FLAG_MAGIC);
      }
    } else {
      const int N = (m <= 256) ? 256 : 512;
      for (int k = 2; k <= N; k <<= 1) {
        for (int j = k >> 1; j > 0; j >>= 1) {
          if (t < N) {
            int l = t ^ j;
            if (l > t) {
              unsigned long long a = skey[t], b2 = skey[l];
              if ((a > b2) == ((t & k) != 0)) { skey[t] = b2; skey[l] = a; }
            }
          }
          __syncthreads();
        }
      }
      if (t < 100) dst[t] = skey[t];
      __threadfence();
      __syncthreads();
      if (t == 0) atomicExch(&flags[ph], FLAG_MAGIC);
    }
    return;
  }

  // ================= merge blocks (one per batch; R8-verified math) =========
  const int b = blk - 192;  // 0..15

  __shared__ unsigned long long qkeys[1200];     // 12 quarter-lists
  __shared__ unsigned long long classlist[300];
  __shared__ int selgi[100];
  __shared__ int selcls[100];
  __shared__ float selsc[100];
  __shared__ float pbuf[100 * 51];

  if (t < 300) classlist[t] = 0ULL;
  if (t < 100) { selgi[t] = -1; selcls[t] = 0; selsc[t] = 0.0f; }
  // spin on the 12 producer flags of this batch (poison 0xAA... != MAGIC)
  if (t < 12)
    while (atomicCAS(&flags[b * 12 + t], FLAG_MAGIC, FLAG_MAGIC) != FLAG_MAGIC)
      __builtin_amdgcn_s_sleep(2);
  __syncthreads();
  // 1200 keys via coherence-point reads (bypass non-coherent L1/L2)
  for (int i = t; i < 1200; i += 1024)
    qkeys[i] = atomicAdd(&s1[b * 1200 + i], 0ULL);
  __syncthreads();

  // merge-4 per class over ALL 1200 entries: rank = own rank + sum
  // cntGT(sibling quarter) on full unique keys -> exact per-class top-100.
  for (int i = t; i < 1200; i += 1024) {
    int c2 = i / 400;          // class
    int qo = (i / 100) & 3;    // own quarter
    int r = i % 100;
    unsigned long long key = qkeys[i];
    if (key != 0ULL) {
      int rank = r;
      #pragma unroll
      for (int qs = 0; qs < 4; ++qs) {
        if (qs == qo) continue;
        const unsigned long long* L = &qkeys[(c2 * 4 + qs) * 100];
        int lo = 0, hi = 100;
        while (lo < hi) {  // first idx with L[mid] <= key -> cntGT
          int mid = (lo + hi) >> 1;
          if (L[mid] > key) lo = mid + 1; else hi = mid;
        }
        rank += lo;
      }
      if (rank < 100) classlist[c2 * 100 + rank] = key;
    }
  }
  __syncthreads();

  // stage-2 (R5/R6/R8-verified): bits desc, class asc, rank asc
  if (t < 300) {
    int c2 = t / 100, r2 = t - c2 * 100;
    unsigned long long key = classlist[t];
    unsigned bits = (unsigned)(key >> 32);
    int rank = r2;
    #pragma unroll
    for (int cp = 0; cp < 3; ++cp) {
      if (cp == c2) continue;
      const unsigned long long* L = classlist + cp * 100;
      int lo = 0, hi = 100;
      while (lo < hi) {  // first idx with bits_i <= bits -> cntGT
        int mid = (lo + hi) >> 1;
        if ((unsigned)(L[mid] >> 32) > bits) lo = mid + 1; else hi = mid;
      }
      int cntGT = lo;
      if (cp < c2) {
        lo = cntGT; hi = 100;
        while (lo < hi) {  // first idx with bits_i < bits -> cntGE
          int mid = (lo + hi) >> 1;
          if ((unsigned)(L[mid] >> 32) >= bits) lo = mid + 1; else hi = mid;
        }
        rank += lo;        // cntGT + cntEQ
      } else {
        rank += cntGT;
      }
    }
    if (rank < 100 && bits != 0u) {
      selgi[rank]  = (int)(0xFFFFFFFFu - (unsigned)(key & 0xFFFFFFFFull));
      selcls[rank] = c2;
      selsc[rank]  = __uint_as_float(bits);
    }
  }
  __syncthreads();

  // cooperative gather: 100 rows x 50 channels, 5 in-flight loads/thread
  const float* rbase = reg + (size_t)b * 50 * HW_;
  {
    float gv[5];
    int gx[5];
    #pragma unroll
    for (int rr2 = 0; rr2 < 5; ++rr2) {
      int idx = rr2 * 1024 + t;
      bool ok = idx < 5000;
      int row = ok ? (idx % 100) : 0;
      int ch  = ok ? (idx / 100) : 0;
      int gi = selgi[row];
      gv[rr2] = (ok && gi >= 0) ? rbase[(size_t)ch * HW_ + gi] : 0.0f;
      gx[rr2] = row * 51 + ch;
    }
    #pragma unroll
    for (int rr2 = 0; rr2 < 5; ++rr2) {
      int idx = rr2 * 1024 + t;
      if (idx < 5000) pbuf[gx[rr2]] = gv[rr2];
    }
  }
  __syncthreads();

  if (t < 100) {
    float* orow = out + ((size_t)b * 100 + t) * 13;
    int gi = selgi[t];
    if (gi < 0) {
      #pragma unroll
      for (int i = 0; i < 13; ++i) orow[i] = 0.0f;
    } else {
      const float* pp = &pbuf[t * 51];
      int cls = selcls[t];
      float score = selsc[t];
      int yy = gi / W_;
      int xx = gi - yy * W_;
      float x = (float)xx, y = (float)yy;

      float fu = calib[b * 4 + 0], cu = calib[b * 4 + 1];
      float fv = calib[b * 4 + 2], cv = calib[b * 4 + 3];
      float pad0 = pad_size[b * 2 + 0], pad1 = pad_size[b * 2 + 1];

      float rA = fmaxf(pp[0], 0.f), rB = fmaxf(pp[1], 0.f);
      float rC = fmaxf(pp[2], 0.f), rD = fmaxf(pp[3], 0.f);
      float bx0 = fminf(fmaxf((x - rA) * 4.f - pad0, 0.f), 1279.f);
      float by0 = fminf(fmaxf((y - rB) * 4.f - pad1, 0.f), 383.f);
      float bx1 = fminf(fmaxf((x + rC) * 4.f - pad0, 0.f), 1279.f);
      float by1 = fminf(fmaxf((y + rD) * 4.f - pad1, 0.f), 383.f);

      float d0 = expf(pp[6]) * dim_mean[cls * 3 + 0];
      float d1 = expf(pp[7]) * dim_mean[cls * 3 + 1];
      float d2 = expf(pp[8]) * dim_mean[cls * 3 + 2];
      float h3d = d1;

      float sig = 1.0f / (1.0f + expf(-pp[48]));
      float ddepth = fminf(fmaxf(1.0f / sig - 1.0f, 0.1f), 100.0f);

      float fh = fu * h3d;
      float d_ctr = fh / (fmaxf(pp[42] - pp[44], 0.f) * 4.f + 1e-6f);
      float d02 = 0.5f * (fh / (fmaxf(pp[26] - pp[34], 0.f) * 4.f + 1e-6f) +
                          fh / (fmaxf(pp[30] - pp[38], 0.f) * 4.f + 1e-6f));
      float d13 = 0.5f * (fh / (fmaxf(pp[28] - pp[36], 0.f) * 4.f + 1e-6f) +
                          fh / (fmaxf(pp[32] - pp[40], 0.f) * 4.f + 1e-6f));
      float kd0 = fminf(fmaxf(d_ctr, 0.1f), 100.f);
      float kd1 = fminf(fmaxf(d02, 0.1f), 100.f);
      float kd2 = fminf(fmaxf(d13, 0.1f), 100.f);

      float u0 = expf(pp[49]), u1 = expf(pp[45]);
      float u2 = expf(pp[46]), u3 = expf(pp[47]);
      float w0 = 1.f / u0, w1 = 1.f / u1, w2 = 1.f / u2, w3 = 1.f / u3;
      float S = w0 + w1 + w2 + w3;
      float depth = (ddepth * w0 + kd0 * w1 + kd1 * w2 + kd2 * w3) / S;
      float derr = (w0 * u0 + w1 * u1 + w2 * u2 + w3 * u3) / S;

      float px = (x + pp[4]) * 4.f - pad0;
      float py = (y + pp[5]) * 4.f - pad1;
      float x3 = (px - cu) * depth / fu;
      float y3 = (py - cv) * depth / fv;

      orow[0] = (float)cls;
      orow[1] = score;
      orow[2] = bx0; orow[3] = by0; orow[4] = bx1; orow[5] = by1;
      orow[6] = d0;  orow[7] = d1;  orow[8] = d2;
      orow[9] = x3;  orow[10] = y3; orow[11] = depth;
      orow[12] = derr;
    }
  }
}

extern "C" void kernel_launch(void* const* d_in, const int* in_sizes, int n_in,
                              void* d_out, int out_size, void* d_ws, size_t ws_size,
                              hipStream_t stream) {
  const float* hmp   = (const float*)d_in[0];  // (16,3,96,320)
  const float* reg   = (const float*)d_in[1];  // (16,50,96,320)
  const float* calib = (const float*)d_in[2];  // (16,4)
  const float* pads  = (const float*)d_in[3];  // (16,2)
  const float* dm    = (const float*)d_in[4];  // (3,3)
  float* out = (float*)d_out;                  // 16*100*13 = 20800 floats

  unsigned long long* s1 = (unsigned long long*)d_ws;  // 192*100*8 = 153,600 B
  int* flags = (int*)((char*)d_ws + 192 * 100 * 8);    // +768 B

  monoflex_all<<<dim3(208), dim3(1024), 0, stream>>>(hmp, reg, calib, pads, dm,
                                                     out, s1, flags);
}